// Round 2
// baseline (668.208 us; speedup 1.0000x reference)
//
#include <hip/hip_runtime.h>
#include <hip/hip_fp16.h>

#define TOKENS 4096
#define NN 2048
#define IN_DIM 1024
#define OUT_DIM 1024
#define TSTEPS 3

typedef _Float16 half8 __attribute__((ext_vector_type(8)));
typedef _Float16 half4 __attribute__((ext_vector_type(4)));
typedef float f32x4 __attribute__((ext_vector_type(4)));

__device__ __forceinline__ void gload_lds16(const void* g, void* l) {
    __builtin_amdgcn_global_load_lds(
        (const __attribute__((address_space(1))) unsigned*)g,
        (__attribute__((address_space(3))) unsigned*)l, 16, 0, 0);
}

// ---------------- generic GEMM (input/output projections) ----------------
// C[M,N] = A[M,K] @ B^T  where B is stored [N,K].
// EPI 1: v += bias; oSta = f16(v); oS = f16(tanh(v))   (input projection)
// EPI 2: C[o] = v + bias                                (output projection)
template<int EPI>
__global__ __launch_bounds__(256)
void gemm_bt(const _Float16* __restrict__ A, const _Float16* __restrict__ B,
             float* __restrict__ C, const float* __restrict__ bias,
             _Float16* __restrict__ oSta, _Float16* __restrict__ oS,
             int M, int N, int K)
{
    __shared__ _Float16 As[128 * 32];
    __shared__ _Float16 Bs[128 * 32];
    const int tid  = threadIdx.x;
    const int wid  = tid >> 6;
    const int lane = tid & 63;
    const int wr = (wid >> 1) * 64;
    const int wc = (wid & 1) * 64;
    const int brow = blockIdx.y * 128;
    const int bcol = blockIdx.x * 128;

    f32x4 acc[4][4];
#pragma unroll
    for (int m = 0; m < 4; ++m)
#pragma unroll
        for (int n = 0; n < 4; ++n) acc[m][n] = (f32x4){0.f, 0.f, 0.f, 0.f};

    const int ldr = tid >> 2;
    const int ldc = (tid & 3) * 8;
    const int wbase = (wid << 4) * 32;
    const int kq = (lane >> 4) * 8;
    const int lr = lane & 15;

    for (int k0 = 0; k0 < K; k0 += 32) {
        __syncthreads();
        gload_lds16(A + (size_t)(brow + ldr) * K + k0 + ldc, As + wbase);
        gload_lds16(A + (size_t)(brow + 64 + ldr) * K + k0 + ldc, As + 64 * 32 + wbase);
        gload_lds16(B + (size_t)(bcol + ldr) * K + k0 + ldc, Bs + wbase);
        gload_lds16(B + (size_t)(bcol + 64 + ldr) * K + k0 + ldc, Bs + 64 * 32 + wbase);
        __syncthreads();

        half8 af[4], bf[4];
#pragma unroll
        for (int m = 0; m < 4; ++m)
            af[m] = *(const half8*)&As[(wr + m * 16 + lr) * 32 + kq];
#pragma unroll
        for (int n = 0; n < 4; ++n)
            bf[n] = *(const half8*)&Bs[(wc + n * 16 + lr) * 32 + kq];
#pragma unroll
        for (int m = 0; m < 4; ++m)
#pragma unroll
            for (int n = 0; n < 4; ++n)
                acc[m][n] = __builtin_amdgcn_mfma_f32_16x16x32_f16(af[m], bf[n], acc[m][n], 0, 0, 0);
    }

    const int cr = (lane >> 4) * 4;
    const int cc = lane & 15;
#pragma unroll
    for (int m = 0; m < 4; ++m) {
#pragma unroll
        for (int n = 0; n < 4; ++n) {
            const int ccol = bcol + wc + n * 16 + cc;
#pragma unroll
            for (int j = 0; j < 4; ++j) {
                const int crow = brow + wr + m * 16 + cr + j;
                float v = acc[m][n][j];
                const size_t o = (size_t)crow * N + ccol;
                if (EPI == 1) {
                    v += bias[ccol];
                    oSta[o] = (_Float16)v;
                    oS[o] = (_Float16)tanhf(v);
                } else {
                    C[o] = v + bias[ccol];
                }
            }
        }
    }
}

// ---------------- fused recurrent step ----------------
// acc1 = state @ effT^T-layout, acc2 = s @ JmT^T-layout (dual GEMM, shared tile),
// epilogue: state' = tanh(acc1 + lam*acc2*s + noise*Tsc); write f16 state', f16 tanh(state').
// Single-barrier double-buffered prefetch: STAGE(next) -> ds_read/MFMA(cur) -> barrier.
__global__ __launch_bounds__(256)
void fused_step(const _Float16* __restrict__ Ast, const _Float16* __restrict__ As_,
                const _Float16* __restrict__ Beff, const _Float16* __restrict__ Bjm,
                const float* __restrict__ noise, const float* __restrict__ Tsc,
                const float* __restrict__ lamp,
                _Float16* __restrict__ stNew, _Float16* __restrict__ sNew)
{
    // LDS: 2 buffers x 4 tiles (A1,A2,B1,B2) x 128x32 f16 = 64 KiB
    __shared__ _Float16 lds[2 * 4 * 4096];
    const int tid  = threadIdx.x;
    const int wid  = tid >> 6;
    const int lane = tid & 63;
    const int wr = (wid >> 1) * 64;
    const int wc = (wid & 1) * 64;
    const int brow = blockIdx.y * 128;
    const int bcol = blockIdx.x * 128;
    const int K = NN;

    f32x4 acc1[4][4], acc2[4][4];
#pragma unroll
    for (int m = 0; m < 4; ++m)
#pragma unroll
        for (int n = 0; n < 4; ++n) {
            acc1[m][n] = (f32x4){0.f, 0.f, 0.f, 0.f};
            acc2[m][n] = (f32x4){0.f, 0.f, 0.f, 0.f};
        }

    const int ldr = tid >> 2;
    const int ldc = (tid & 3) * 8;
    const int wbase = (wid << 4) * 32;   // wave-uniform LDS base (f16 elems)
    const int kq = (lane >> 4) * 8;
    const int lr = lane & 15;

    auto stage = [&](int b, int k0) {
        _Float16* base = &lds[b * 16384];
        const size_t gr  = (size_t)(brow + ldr) * K + k0 + ldc;
        const size_t gr2 = (size_t)(brow + 64 + ldr) * K + k0 + ldc;
        const size_t gc  = (size_t)(bcol + ldr) * K + k0 + ldc;
        const size_t gc2 = (size_t)(bcol + 64 + ldr) * K + k0 + ldc;
        gload_lds16(Ast + gr,  base + 0 * 4096 + wbase);
        gload_lds16(Ast + gr2, base + 0 * 4096 + 2048 + wbase);
        gload_lds16(As_ + gr,  base + 1 * 4096 + wbase);
        gload_lds16(As_ + gr2, base + 1 * 4096 + 2048 + wbase);
        gload_lds16(Beff + gc,  base + 2 * 4096 + wbase);
        gload_lds16(Beff + gc2, base + 2 * 4096 + 2048 + wbase);
        gload_lds16(Bjm + gc,  base + 3 * 4096 + wbase);
        gload_lds16(Bjm + gc2, base + 3 * 4096 + 2048 + wbase);
    };

    stage(0, 0);
    __syncthreads();   // drains vmcnt(0): buffer 0 ready

    int cur = 0;
    for (int k0 = 0; k0 < K; k0 += 32, cur ^= 1) {
        if (k0 + 32 < K) stage(cur ^ 1, k0 + 32);   // async loads overlap compute below

        const _Float16* base = &lds[cur * 16384];
        half8 a1[4], b1[4], a2[4], b2[4];
#pragma unroll
        for (int m = 0; m < 4; ++m)
            a1[m] = *(const half8*)&base[0 * 4096 + (wr + m * 16 + lr) * 32 + kq];
#pragma unroll
        for (int n = 0; n < 4; ++n)
            b1[n] = *(const half8*)&base[2 * 4096 + (wc + n * 16 + lr) * 32 + kq];
#pragma unroll
        for (int m = 0; m < 4; ++m)
#pragma unroll
            for (int n = 0; n < 4; ++n)
                acc1[m][n] = __builtin_amdgcn_mfma_f32_16x16x32_f16(a1[m], b1[n], acc1[m][n], 0, 0, 0);
#pragma unroll
        for (int m = 0; m < 4; ++m)
            a2[m] = *(const half8*)&base[1 * 4096 + (wr + m * 16 + lr) * 32 + kq];
#pragma unroll
        for (int n = 0; n < 4; ++n)
            b2[n] = *(const half8*)&base[3 * 4096 + (wc + n * 16 + lr) * 32 + kq];
#pragma unroll
        for (int m = 0; m < 4; ++m)
#pragma unroll
            for (int n = 0; n < 4; ++n)
                acc2[m][n] = __builtin_amdgcn_mfma_f32_16x16x32_f16(a2[m], b2[n], acc2[m][n], 0, 0, 0);

        __syncthreads();   // drains stage loads (buffer cur^1 ready) + protects reuse
    }

    // epilogue: fused elementwise step. C/D layout: col=lane&15, row=(lane>>4)*4+j
    const float lam = lamp[0];
    const int cr = (lane >> 4) * 4;
    const int cc = lane & 15;
#pragma unroll
    for (int m = 0; m < 4; ++m) {
#pragma unroll
        for (int n = 0; n < 4; ++n) {
            const int ccol = bcol + wc + n * 16 + cc;
            const float tv = Tsc[ccol];
#pragma unroll
            for (int j = 0; j < 4; ++j) {
                const int crow = brow + wr + m * 16 + cr + j;
                const size_t o = (size_t)crow * NN + ccol;
                float s = (float)As_[o];
                float arg = acc1[m][n][j] + lam * (acc2[m][n][j] * s) + noise[o] * tv;
                float st = tanhf(arg);
                stNew[o] = (_Float16)st;
                sNew[o]  = (_Float16)tanhf(st);
            }
        }
    }
}

// ---------------- small prep kernels ----------------
__global__ void cvt_f16(const float* __restrict__ in, _Float16* __restrict__ out, int n4) {
    int i = blockIdx.x * blockDim.x + threadIdx.x;
    if (i < n4) {
        f32x4 v = *(const f32x4*)&in[(size_t)i * 4];
        half4 h;
        h[0] = (_Float16)v[0]; h[1] = (_Float16)v[1];
        h[2] = (_Float16)v[2]; h[3] = (_Float16)v[3];
        *(half4*)&out[(size_t)i * 4] = h;
    }
}

__global__ void transmul2(const float* __restrict__ W, const float* __restrict__ J,
                          const float* __restrict__ Mk,
                          _Float16* __restrict__ effT, _Float16* __restrict__ JmT) {
    __shared__ float tw[32][33];
    __shared__ float tj[32][33];
    const int bx = blockIdx.x * 32, by = blockIdx.y * 32;
    const int tx = threadIdx.x, ty0 = threadIdx.y;
#pragma unroll
    for (int r = 0; r < 4; ++r) {
        int ty = ty0 + r * 8;
        size_t idx = (size_t)(by + ty) * NN + bx + tx;
        float mv = Mk[idx];
        tw[ty][tx] = W[idx] * mv;
        tj[ty][tx] = J[idx] * mv;
    }
    __syncthreads();
#pragma unroll
    for (int r = 0; r < 4; ++r) {
        int ty = ty0 + r * 8;
        size_t o = (size_t)(bx + ty) * NN + by + tx;
        effT[o] = (_Float16)tw[tx][ty];
        JmT[o]  = (_Float16)tj[tx][ty];
    }
}

__global__ void tsc_kernel(const float* __restrict__ theta, float* __restrict__ Tsc) {
    int i = blockIdx.x * blockDim.x + threadIdx.x;
    if (i < NN) Tsc[i] = fabsf(sinf(2.0f * theta[i])) * 0.1f;
}

extern "C" void kernel_launch(void* const* d_in, const int* in_sizes, int n_in,
                              void* d_out, int out_size, void* d_ws, size_t ws_size,
                              hipStream_t stream) {
    const float* x       = (const float*)d_in[0];
    const float* W_in    = (const float*)d_in[1];
    const float* b_in    = (const float*)d_in[2];
    const float* weights = (const float*)d_in[3];
    const float* Jmat    = (const float*)d_in[4];
    const float* theta   = (const float*)d_in[5];
    const float* lam     = (const float*)d_in[6];
    const float* mask    = (const float*)d_in[7];
    const float* noise   = (const float*)d_in[8];
    const float* W_out   = (const float*)d_in[9];
    const float* b_out   = (const float*)d_in[10];
    float* out = (float*)d_out;

    char* w = (char*)d_ws;
    auto alloc = [&](size_t b) { char* p = w; w += (b + 255) & ~(size_t)255; return p; };
    _Float16* xh     = (_Float16*)alloc((size_t)TOKENS * IN_DIM * 2);
    _Float16* WinH   = (_Float16*)alloc((size_t)NN * IN_DIM * 2);
    _Float16* WoutH  = (_Float16*)alloc((size_t)OUT_DIM * NN * 2);
    _Float16* effT   = (_Float16*)alloc((size_t)NN * NN * 2);
    _Float16* JmT    = (_Float16*)alloc((size_t)NN * NN * 2);
    _Float16* stA    = (_Float16*)alloc((size_t)TOKENS * NN * 2);
    _Float16* sA     = (_Float16*)alloc((size_t)TOKENS * NN * 2);
    _Float16* stB    = (_Float16*)alloc((size_t)TOKENS * NN * 2);
    _Float16* sB     = (_Float16*)alloc((size_t)TOKENS * NN * 2);
    float* Tsc       = (float*)alloc((size_t)NN * 4);

    cvt_f16<<<TOKENS * IN_DIM / 4 / 256, 256, 0, stream>>>(x, xh, TOKENS * IN_DIM / 4);
    cvt_f16<<<NN * IN_DIM / 4 / 256, 256, 0, stream>>>(W_in, WinH, NN * IN_DIM / 4);
    cvt_f16<<<OUT_DIM * NN / 4 / 256, 256, 0, stream>>>(W_out, WoutH, OUT_DIM * NN / 4);
    transmul2<<<dim3(NN / 32, NN / 32), dim3(32, 8), 0, stream>>>(weights, Jmat, mask, effT, JmT);
    tsc_kernel<<<NN / 256, 256, 0, stream>>>(theta, Tsc);

    // state = x @ W_in.T + b_in
    gemm_bt<1><<<dim3(NN / 128, TOKENS / 128), 256, 0, stream>>>(
        xh, WinH, nullptr, b_in, stA, sA, TOKENS, NN, IN_DIM);

    for (int t = 0; t < TSTEPS; ++t) {
        fused_step<<<dim3(NN / 128, TOKENS / 128), 256, 0, stream>>>(
            stA, sA, effT, JmT, noise + (size_t)t * TOKENS * NN, Tsc, lam, stB, sB);
        _Float16* tmp;
        tmp = stA; stA = stB; stB = tmp;
        tmp = sA;  sA = sB;  sB = tmp;
    }

    // out = state @ W_out.T + b_out
    gemm_bt<2><<<dim3(OUT_DIM / 128, TOKENS / 128), 256, 0, stream>>>(
        stA, WoutH, out, b_out, nullptr, nullptr, TOKENS, OUT_DIM, NN);
}

// Round 3
// 413.160 us; speedup vs baseline: 1.6173x; 1.6173x over previous
//
#include <hip/hip_runtime.h>
#include <hip/hip_fp16.h>

#define TOKENS 4096
#define NN 2048
#define IN_DIM 1024
#define OUT_DIM 1024
#define TSTEPS 3

typedef _Float16 half8 __attribute__((ext_vector_type(8)));
typedef _Float16 half4 __attribute__((ext_vector_type(4)));
typedef float f32x4 __attribute__((ext_vector_type(4)));

__device__ __forceinline__ void gload_lds16(const void* g, void* l) {
    __builtin_amdgcn_global_load_lds(
        (const __attribute__((address_space(1))) unsigned*)g,
        (__attribute__((address_space(3))) unsigned*)l, 16, 0, 0);
}

// ================= pipelined dual GEMM (recurrent step) =================
// 256 blocks x 512 threads. Blocks [0,128): C0 = A0 @ B0^T-layout;
// blocks [128,256): C1 = A1 @ B1^T-layout. All matrices f16, K = NN = 2048,
// B stored [N][K]. Tile 256x256, BK=32, 8 waves (2M x 4N), wave tile 128x64.
// 4-deep LDS buffer ring; loads stay 3 tiles ahead; counted vmcnt (never 0
// in steady state); raw s_barrier (no drain); LDS XOR swizzle (2-way = free).
__global__ __launch_bounds__(512, 2)
void dual_gemm(const _Float16* __restrict__ A0, const _Float16* __restrict__ B0,
               float* __restrict__ C0,
               const _Float16* __restrict__ A1, const _Float16* __restrict__ B1,
               float* __restrict__ C1)
{
    // 4 bufs x (A 8192 + B 8192) f16 = 128 KiB
    __shared__ __align__(16) _Float16 lds[4 * 16384];
    const int tid  = threadIdx.x;
    const int wid  = tid >> 6;
    const int lane = tid & 63;

    int bid = blockIdx.x;
    const int g = bid >> 7;
    bid &= 127;
    const int bx = bid & 7;     // N/256 = 8
    const int by = bid >> 3;    // M/256 = 16
    const _Float16* __restrict__ A = g ? A1 : A0;
    const _Float16* __restrict__ B = g ? B1 : B0;
    float* __restrict__ C = g ? C1 : C0;
    const int brow = by << 8;
    const int bcol = bx << 8;

    // ---- staging geometry: call = 8 KB = 128 rows x 64 B; 2 calls per matrix-tile.
    // thread t: row = t>>2, physical col16 = t&3; fetch pre-swizzled (inverse =
    // same XOR) logical col16 = (t&3) ^ ((row>>1)&3) = (t&3) ^ ((t>>3)&3).
    const int sr = tid >> 2;
    const int sc = ((tid & 3) ^ ((tid >> 3) & 3)) << 3;
    const _Float16* gA = A + (size_t)(brow + sr) * NN + sc;
    const _Float16* gB = B + (size_t)(bcol + sr) * NN + sc;
    const int ldst = wid << 9;   // wave-uniform slice base within a call (f16)

    auto stage = [&](int u) {
        _Float16* l = lds + (u & 3) * 16384;
        const _Float16* a = gA + u * 32;
        const _Float16* b = gB + u * 32;
        gload_lds16(a,            l + ldst);
        gload_lds16(a + 128 * NN, l + 4096  + ldst);
        gload_lds16(b,            l + 8192  + ldst);
        gload_lds16(b + 128 * NN, l + 12288 + ldst);
    };

    // ---- read geometry: row R -> physical col16 = logical col16 ^ ((R>>1)&3).
    // For R = wbase + m*16 + lr this reduces to ^((lr>>1)&3): 2-way banks = free.
    const int wr = (wid >> 2) << 7;   // 0 / 128
    const int wc = (wid & 3) << 6;    // 0 / 64 / 128 / 192
    const int lr = lane & 15;
    const int swz = ((lane >> 4) ^ ((lr >> 1) & 3)) << 3;
    const int aRd = (wr + lr) * 32 + swz;          // + m*512
    const int bRd = 8192 + (wc + lr) * 32 + swz;   // + n*512

    f32x4 acc[8][4];
#pragma unroll
    for (int m = 0; m < 8; ++m)
#pragma unroll
        for (int n = 0; n < 4; ++n) acc[m][n] = (f32x4){0.f, 0.f, 0.f, 0.f};

    stage(0); stage(1); stage(2);   // prime: 3 tiles in flight (12 loads)

    for (int t = 0; t < 64; ++t) {
        // keep 3 tiles ahead; counted waits guarantee tile t resident
        if (t < 61) {
            stage(t + 3);
            asm volatile("s_waitcnt vmcnt(12)" ::: "memory");
        } else if (t == 61) {
            asm volatile("s_waitcnt vmcnt(8)" ::: "memory");
        } else if (t == 62) {
            asm volatile("s_waitcnt vmcnt(4)" ::: "memory");
        } else {
            asm volatile("s_waitcnt vmcnt(0)" ::: "memory");
        }
        __builtin_amdgcn_s_barrier();          // all waves' tile-t slices visible
        asm volatile("" ::: "memory");
        __builtin_amdgcn_sched_barrier(0);     // pin: no reads hoist above barrier

        const _Float16* lb = lds + (t & 3) * 16384;
        half8 bf[4];
#pragma unroll
        for (int n = 0; n < 4; ++n)
            bf[n] = *(const half8*)&lb[bRd + (n << 9)];
        __builtin_amdgcn_s_setprio(1);
#pragma unroll
        for (int m = 0; m < 8; ++m) {
            half8 af = *(const half8*)&lb[aRd + (m << 9)];
#pragma unroll
            for (int n = 0; n < 4; ++n)
                acc[m][n] = __builtin_amdgcn_mfma_f32_16x16x32_f16(af, bf[n], acc[m][n], 0, 0, 0);
        }
        __builtin_amdgcn_s_setprio(0);
        __builtin_amdgcn_sched_barrier(0);
        asm volatile("" ::: "memory");
        __builtin_amdgcn_s_barrier();          // reads done before buf reuse
    }

    // epilogue: C/D layout col=lane&15, row=(lane>>4)*4+j  [m89-verified]
    const int cr = (lane >> 4) << 2;
    const int cc = lane & 15;
#pragma unroll
    for (int m = 0; m < 8; ++m) {
#pragma unroll
        for (int n = 0; n < 4; ++n) {
            const size_t o0 = (size_t)(brow + wr + m * 16 + cr) * NN
                            + (bcol + wc + n * 16 + cc);
#pragma unroll
            for (int j = 0; j < 4; ++j)
                C[o0 + (size_t)j * NN] = acc[m][n][j];
        }
    }
}

// ================= generic GEMM (input/output projections) =================
// EPI 1: v += bias; oSta = f16(v); oS = f16(tanh(v))
// EPI 2: C[o] = v + bias
template<int EPI>
__global__ __launch_bounds__(256)
void gemm_bt(const _Float16* __restrict__ A, const _Float16* __restrict__ B,
             float* __restrict__ C, const float* __restrict__ bias,
             _Float16* __restrict__ oSta, _Float16* __restrict__ oS,
             int M, int N, int K)
{
    __shared__ _Float16 As[128 * 32];
    __shared__ _Float16 Bs[128 * 32];
    const int tid  = threadIdx.x;
    const int wid  = tid >> 6;
    const int lane = tid & 63;
    const int wr = (wid >> 1) * 64;
    const int wc = (wid & 1) * 64;
    const int brow = blockIdx.y * 128;
    const int bcol = blockIdx.x * 128;

    f32x4 acc[4][4];
#pragma unroll
    for (int m = 0; m < 4; ++m)
#pragma unroll
        for (int n = 0; n < 4; ++n) acc[m][n] = (f32x4){0.f, 0.f, 0.f, 0.f};

    const int ldr = tid >> 2;
    const int ldc = (tid & 3) * 8;
    const int wbase = (wid << 4) * 32;
    const int kq = (lane >> 4) * 8;
    const int lr = lane & 15;

    for (int k0 = 0; k0 < K; k0 += 32) {
        __syncthreads();
        gload_lds16(A + (size_t)(brow + ldr) * K + k0 + ldc, As + wbase);
        gload_lds16(A + (size_t)(brow + 64 + ldr) * K + k0 + ldc, As + 64 * 32 + wbase);
        gload_lds16(B + (size_t)(bcol + ldr) * K + k0 + ldc, Bs + wbase);
        gload_lds16(B + (size_t)(bcol + 64 + ldr) * K + k0 + ldc, Bs + 64 * 32 + wbase);
        __syncthreads();

        half8 af[4], bf[4];
#pragma unroll
        for (int m = 0; m < 4; ++m)
            af[m] = *(const half8*)&As[(wr + m * 16 + lr) * 32 + kq];
#pragma unroll
        for (int n = 0; n < 4; ++n)
            bf[n] = *(const half8*)&Bs[(wc + n * 16 + lr) * 32 + kq];
#pragma unroll
        for (int m = 0; m < 4; ++m)
#pragma unroll
            for (int n = 0; n < 4; ++n)
                acc[m][n] = __builtin_amdgcn_mfma_f32_16x16x32_f16(af[m], bf[n], acc[m][n], 0, 0, 0);
    }

    const int cr = (lane >> 4) * 4;
    const int cc = lane & 15;
#pragma unroll
    for (int m = 0; m < 4; ++m) {
#pragma unroll
        for (int n = 0; n < 4; ++n) {
            const int ccol = bcol + wc + n * 16 + cc;
#pragma unroll
            for (int j = 0; j < 4; ++j) {
                const int crow = brow + wr + m * 16 + cr + j;
                float v = acc[m][n][j];
                const size_t o = (size_t)crow * N + ccol;
                if (EPI == 1) {
                    v += bias[ccol];
                    oSta[o] = (_Float16)v;
                    oS[o] = (_Float16)tanhf(v);
                } else {
                    C[o] = v + bias[ccol];
                }
            }
        }
    }
}

// ================= small prep / elementwise kernels =================
__global__ void cvt_f16(const float* __restrict__ in, _Float16* __restrict__ out, int n4) {
    int i = blockIdx.x * blockDim.x + threadIdx.x;
    if (i < n4) {
        f32x4 v = *(const f32x4*)&in[(size_t)i * 4];
        half4 h;
        h[0] = (_Float16)v[0]; h[1] = (_Float16)v[1];
        h[2] = (_Float16)v[2]; h[3] = (_Float16)v[3];
        *(half4*)&out[(size_t)i * 4] = h;
    }
}

__global__ void transmul2(const float* __restrict__ W, const float* __restrict__ J,
                          const float* __restrict__ Mk,
                          _Float16* __restrict__ effT, _Float16* __restrict__ JmT) {
    __shared__ float tw[32][33];
    __shared__ float tj[32][33];
    const int bx = blockIdx.x * 32, by = blockIdx.y * 32;
    const int tx = threadIdx.x, ty0 = threadIdx.y;
#pragma unroll
    for (int r = 0; r < 4; ++r) {
        int ty = ty0 + r * 8;
        size_t idx = (size_t)(by + ty) * NN + bx + tx;
        float mv = Mk[idx];
        tw[ty][tx] = W[idx] * mv;
        tj[ty][tx] = J[idx] * mv;
    }
    __syncthreads();
#pragma unroll
    for (int r = 0; r < 4; ++r) {
        int ty = ty0 + r * 8;
        size_t o = (size_t)(bx + ty) * NN + by + tx;
        effT[o] = (_Float16)tw[tx][ty];
        JmT[o]  = (_Float16)tj[tx][ty];
    }
}

__global__ void tsc_kernel(const float* __restrict__ theta, float* __restrict__ Tsc) {
    int i = blockIdx.x * blockDim.x + threadIdx.x;
    if (i < NN) Tsc[i] = fabsf(sinf(2.0f * theta[i])) * 0.1f;
}

__global__ void step_kernel(const float* __restrict__ signal, const float* __restrict__ sJ,
                            const float* __restrict__ noise, const float* __restrict__ Tsc,
                            const float* __restrict__ lamp,
                            _Float16* __restrict__ stateH, _Float16* __restrict__ sH) {
    const int i4 = blockIdx.x * blockDim.x + threadIdx.x;
    const float lam = lamp[0];
    const size_t base = (size_t)i4 * 4;
    f32x4 sg = *(const f32x4*)&signal[base];
    f32x4 dj = *(const f32x4*)&sJ[base];
    f32x4 nz = *(const f32x4*)&noise[base];
    const int col4 = (int)(base & (NN - 1));
    f32x4 tv = *(const f32x4*)&Tsc[col4];
    half4 so = *(const half4*)&sH[base];
    half4 hs, hn;
#pragma unroll
    for (int j = 0; j < 4; ++j) {
        float s = (float)so[j];
        float arg = sg[j] + lam * (dj[j] * s) + nz[j] * tv[j];
        float st = tanhf(arg);
        hs[j] = (_Float16)st;
        hn[j] = (_Float16)tanhf(st);
    }
    *(half4*)&stateH[base] = hs;
    *(half4*)&sH[base] = hn;
}

extern "C" void kernel_launch(void* const* d_in, const int* in_sizes, int n_in,
                              void* d_out, int out_size, void* d_ws, size_t ws_size,
                              hipStream_t stream) {
    const float* x       = (const float*)d_in[0];
    const float* W_in    = (const float*)d_in[1];
    const float* b_in    = (const float*)d_in[2];
    const float* weights = (const float*)d_in[3];
    const float* Jmat    = (const float*)d_in[4];
    const float* theta   = (const float*)d_in[5];
    const float* lam     = (const float*)d_in[6];
    const float* mask    = (const float*)d_in[7];
    const float* noise   = (const float*)d_in[8];
    const float* W_out   = (const float*)d_in[9];
    const float* b_out   = (const float*)d_in[10];
    float* out = (float*)d_out;

    char* w = (char*)d_ws;
    auto alloc = [&](size_t b) { char* p = w; w += (b + 255) & ~(size_t)255; return p; };
    _Float16* xh     = (_Float16*)alloc((size_t)TOKENS * IN_DIM * 2);
    _Float16* WinH   = (_Float16*)alloc((size_t)NN * IN_DIM * 2);
    _Float16* WoutH  = (_Float16*)alloc((size_t)OUT_DIM * NN * 2);
    _Float16* effT   = (_Float16*)alloc((size_t)NN * NN * 2);
    _Float16* JmT    = (_Float16*)alloc((size_t)NN * NN * 2);
    _Float16* stateH = (_Float16*)alloc((size_t)TOKENS * NN * 2);
    _Float16* sH     = (_Float16*)alloc((size_t)TOKENS * NN * 2);
    float* Tsc       = (float*)alloc((size_t)NN * 4);
    float* signal    = (float*)alloc((size_t)TOKENS * NN * 4);
    float* sJ        = (float*)alloc((size_t)TOKENS * NN * 4);

    cvt_f16<<<TOKENS * IN_DIM / 4 / 256, 256, 0, stream>>>(x, xh, TOKENS * IN_DIM / 4);
    cvt_f16<<<NN * IN_DIM / 4 / 256, 256, 0, stream>>>(W_in, WinH, NN * IN_DIM / 4);
    cvt_f16<<<OUT_DIM * NN / 4 / 256, 256, 0, stream>>>(W_out, WoutH, OUT_DIM * NN / 4);
    transmul2<<<dim3(NN / 32, NN / 32), dim3(32, 8), 0, stream>>>(weights, Jmat, mask, effT, JmT);
    tsc_kernel<<<NN / 256, 256, 0, stream>>>(theta, Tsc);

    // state = x @ W_in.T + b_in
    gemm_bt<1><<<dim3(NN / 128, TOKENS / 128), 256, 0, stream>>>(
        xh, WinH, nullptr, b_in, stateH, sH, TOKENS, NN, IN_DIM);

    for (int t = 0; t < TSTEPS; ++t) {
        dual_gemm<<<256, 512, 0, stream>>>(stateH, effT, signal, sH, JmT, sJ);
        step_kernel<<<TOKENS * NN / 4 / 256, 256, 0, stream>>>(
            signal, sJ, noise + (size_t)t * TOKENS * NN, Tsc, lam, stateH, sH);
    }

    // out = state @ W_out.T + b_out
    gemm_bt<2><<<dim3(OUT_DIM / 128, TOKENS / 128), 256, 0, stream>>>(
        stateH, WoutH, out, b_out, nullptr, nullptr, TOKENS, OUT_DIM, NN);
}

// Round 4
// 391.794 us; speedup vs baseline: 1.7055x; 1.0545x over previous
//
#include <hip/hip_runtime.h>
#include <hip/hip_fp16.h>

#define TOKENS 4096
#define NN 2048
#define IN_DIM 1024
#define OUT_DIM 1024
#define TSTEPS 3

typedef _Float16 half8 __attribute__((ext_vector_type(8)));
typedef _Float16 half4 __attribute__((ext_vector_type(4)));
typedef float f32x4 __attribute__((ext_vector_type(4)));

__device__ __forceinline__ void gload_lds16(const void* g, void* l) {
    __builtin_amdgcn_global_load_lds(
        (const __attribute__((address_space(1))) unsigned*)g,
        (__attribute__((address_space(3))) unsigned*)l, 16, 0, 0);
}

// ================= pipelined dual GEMM (recurrent step) =================
// 256 blocks x 512 threads. Blocks [0,128): C0 = A0 @ B0^T-layout;
// blocks [128,256): C1 = A1 @ B1^T-layout. f16, K = NN = 2048, B stored [N][K].
// Tile 256x256, BK=32, 8 waves (2M x 4N), wave tile 128x64.
// 4-deep LDS ring, 3 tiles prefetch-ahead, counted vmcnt at iteration END
// (tile t+1 residency proven before its reads issue). Fine phase interleave
// (m201-style): 2 phases/K-tile, each {ds_read, stage, bar, lgkm0, 16 MFMA, bar}.
__global__ __launch_bounds__(512, 2)
void dual_gemm(const _Float16* __restrict__ A0, const _Float16* __restrict__ B0,
               float* __restrict__ C0,
               const _Float16* __restrict__ A1, const _Float16* __restrict__ B1,
               float* __restrict__ C1)
{
    // 4 bufs x (A 8192 + B 8192) f16 = 128 KiB
    __shared__ __align__(16) _Float16 lds[4 * 16384];
    const int tid  = threadIdx.x;
    const int wid  = tid >> 6;
    const int lane = tid & 63;

    int bid = blockIdx.x;
    const int g = bid >> 7;
    bid &= 127;
    const int bx = bid & 7;     // N/256 = 8
    const int by = bid >> 3;    // M/256 = 16
    const _Float16* __restrict__ A = g ? A1 : A0;
    const _Float16* __restrict__ B = g ? B1 : B0;
    float* __restrict__ C = g ? C1 : C0;
    const int brow = by << 8;
    const int bcol = bx << 8;

    // staging geometry: call = 8 KB = 128 rows x 64 B.
    // thread t: row = t>>2, physical col16 = t&3; fetch pre-swizzled logical
    // col16 = (t&3) ^ ((t>>3)&3)  (involution; inverse = same XOR).
    const int sr = tid >> 2;
    const int sc = ((tid & 3) ^ ((tid >> 3) & 3)) << 3;
    const _Float16* gA = A + (size_t)(brow + sr) * NN + sc;
    const _Float16* gB = B + (size_t)(bcol + sr) * NN + sc;
    const int ldst = wid << 9;   // wave-uniform slice base within a call (f16)

    auto stageA = [&](int u) {
        _Float16* l = lds + (u & 3) * 16384;
        const _Float16* a = gA + u * 32;
        gload_lds16(a,            l + ldst);
        gload_lds16(a + 128 * NN, l + 4096 + ldst);
    };
    auto stageB = [&](int u) {
        _Float16* l = lds + (u & 3) * 16384;
        const _Float16* b = gB + u * 32;
        gload_lds16(b,            l + 8192  + ldst);
        gload_lds16(b + 128 * NN, l + 12288 + ldst);
    };

    // read geometry: row R -> phys col16 = logical ^ ((R>>1)&3) = ^((lr>>1)&3).
    const int wr = (wid >> 2) << 7;   // 0 / 128
    const int wc = (wid & 3) << 6;    // 0 / 64 / 128 / 192
    const int lr = lane & 15;
    const int swz = ((lane >> 4) ^ ((lr >> 1) & 3)) << 3;
    const int aRd = (wr + lr) * 32 + swz;          // + m*512
    const int bRd = 8192 + (wc + lr) * 32 + swz;   // + n*512

    f32x4 acc[8][4];
#pragma unroll
    for (int m = 0; m < 8; ++m)
#pragma unroll
        for (int n = 0; n < 4; ++n) acc[m][n] = (f32x4){0.f, 0.f, 0.f, 0.f};

    // prime: 3 tiles in flight (12 calls); wait until tile 0's 4 are done
    stageA(0); stageB(0); stageA(1); stageB(1); stageA(2); stageB(2);
    asm volatile("s_waitcnt vmcnt(8)" ::: "memory");
    __builtin_amdgcn_s_barrier();

    for (int t = 0; t < 64; ++t) {
        const _Float16* lb = lds + (t & 3) * 16384;

        // ---------------- phase 1: m0-3 x n0-3 ----------------
        half8 af[4], bf[4];
#pragma unroll
        for (int m = 0; m < 4; ++m)
            af[m] = *(const half8*)&lb[aRd + (m << 9)];
#pragma unroll
        for (int n = 0; n < 4; ++n)
            bf[n] = *(const half8*)&lb[bRd + (n << 9)];
        if (t < 61) stageA(t + 3);
        __builtin_amdgcn_s_barrier();
        asm volatile("s_waitcnt lgkmcnt(0)" ::: "memory");
        __builtin_amdgcn_sched_barrier(0);
        __builtin_amdgcn_s_setprio(1);
#pragma unroll
        for (int m = 0; m < 4; ++m)
#pragma unroll
            for (int n = 0; n < 4; ++n)
                acc[m][n] = __builtin_amdgcn_mfma_f32_16x16x32_f16(af[m], bf[n], acc[m][n], 0, 0, 0);
        __builtin_amdgcn_s_setprio(0);
        __builtin_amdgcn_sched_barrier(0);
        __builtin_amdgcn_s_barrier();

        // ---------------- phase 2: m4-7 x n0-3 (B regs reused) ----------------
#pragma unroll
        for (int m = 0; m < 4; ++m)
            af[m] = *(const half8*)&lb[aRd + ((m + 4) << 9)];
        if (t < 61) stageB(t + 3);
        __builtin_amdgcn_s_barrier();
        asm volatile("s_waitcnt lgkmcnt(0)" ::: "memory");
        __builtin_amdgcn_sched_barrier(0);
        __builtin_amdgcn_s_setprio(1);
#pragma unroll
        for (int m = 0; m < 4; ++m)
#pragma unroll
            for (int n = 0; n < 4; ++n)
                acc[m + 4][n] = __builtin_amdgcn_mfma_f32_16x16x32_f16(af[m], bf[n], acc[m + 4][n], 0, 0, 0);
        __builtin_amdgcn_s_setprio(0);
        __builtin_amdgcn_sched_barrier(0);

        // prove tile t+1 resident before next iteration's reads issue
        if (t < 61)      asm volatile("s_waitcnt vmcnt(8)" ::: "memory");
        else if (t == 61) asm volatile("s_waitcnt vmcnt(4)" ::: "memory");
        else if (t == 62) asm volatile("s_waitcnt vmcnt(0)" ::: "memory");
        __builtin_amdgcn_s_barrier();
    }

    // epilogue: C/D layout col=lane&15, row=(lane>>4)*4+j  [m89-verified]
    const int cr = (lane >> 4) << 2;
    const int cc = lane & 15;
#pragma unroll
    for (int m = 0; m < 8; ++m) {
#pragma unroll
        for (int n = 0; n < 4; ++n) {
            const size_t o0 = (size_t)(brow + wr + m * 16 + cr) * NN
                            + (bcol + wc + n * 16 + cc);
#pragma unroll
            for (int j = 0; j < 4; ++j)
                C[o0 + (size_t)j * NN] = acc[m][n][j];
        }
    }
}

// ================= generic GEMM (input/output projections) =================
// EPI 1: v += bias; oSta = f16(v); oS = f16(tanh(v))
// EPI 2: C[o] = v + bias
template<int EPI>
__global__ __launch_bounds__(256)
void gemm_bt(const _Float16* __restrict__ A, const _Float16* __restrict__ B,
             float* __restrict__ C, const float* __restrict__ bias,
             _Float16* __restrict__ oSta, _Float16* __restrict__ oS,
             int M, int N, int K)
{
    __shared__ _Float16 As[128 * 32];
    __shared__ _Float16 Bs[128 * 32];
    const int tid  = threadIdx.x;
    const int wid  = tid >> 6;
    const int lane = tid & 63;
    const int wr = (wid >> 1) * 64;
    const int wc = (wid & 1) * 64;
    const int brow = blockIdx.y * 128;
    const int bcol = blockIdx.x * 128;

    f32x4 acc[4][4];
#pragma unroll
    for (int m = 0; m < 4; ++m)
#pragma unroll
        for (int n = 0; n < 4; ++n) acc[m][n] = (f32x4){0.f, 0.f, 0.f, 0.f};

    const int ldr = tid >> 2;
    const int ldc = (tid & 3) * 8;
    const int wbase = (wid << 4) * 32;
    const int kq = (lane >> 4) * 8;
    const int lr = lane & 15;

    for (int k0 = 0; k0 < K; k0 += 32) {
        __syncthreads();
        gload_lds16(A + (size_t)(brow + ldr) * K + k0 + ldc, As + wbase);
        gload_lds16(A + (size_t)(brow + 64 + ldr) * K + k0 + ldc, As + 64 * 32 + wbase);
        gload_lds16(B + (size_t)(bcol + ldr) * K + k0 + ldc, Bs + wbase);
        gload_lds16(B + (size_t)(bcol + 64 + ldr) * K + k0 + ldc, Bs + 64 * 32 + wbase);
        __syncthreads();

        half8 af[4], bf[4];
#pragma unroll
        for (int m = 0; m < 4; ++m)
            af[m] = *(const half8*)&As[(wr + m * 16 + lr) * 32 + kq];
#pragma unroll
        for (int n = 0; n < 4; ++n)
            bf[n] = *(const half8*)&Bs[(wc + n * 16 + lr) * 32 + kq];
#pragma unroll
        for (int m = 0; m < 4; ++m)
#pragma unroll
            for (int n = 0; n < 4; ++n)
                acc[m][n] = __builtin_amdgcn_mfma_f32_16x16x32_f16(af[m], bf[n], acc[m][n], 0, 0, 0);
    }

    const int cr = (lane >> 4) * 4;
    const int cc = lane & 15;
#pragma unroll
    for (int m = 0; m < 4; ++m) {
#pragma unroll
        for (int n = 0; n < 4; ++n) {
            const int ccol = bcol + wc + n * 16 + cc;
#pragma unroll
            for (int j = 0; j < 4; ++j) {
                const int crow = brow + wr + m * 16 + cr + j;
                float v = acc[m][n][j];
                const size_t o = (size_t)crow * N + ccol;
                if (EPI == 1) {
                    v += bias[ccol];
                    oSta[o] = (_Float16)v;
                    oS[o] = (_Float16)tanhf(v);
                } else {
                    C[o] = v + bias[ccol];
                }
            }
        }
    }
}

// ================= small prep / elementwise kernels =================
__global__ void cvt_f16(const float* __restrict__ in, _Float16* __restrict__ out, int n4) {
    int i = blockIdx.x * blockDim.x + threadIdx.x;
    if (i < n4) {
        f32x4 v = *(const f32x4*)&in[(size_t)i * 4];
        half4 h;
        h[0] = (_Float16)v[0]; h[1] = (_Float16)v[1];
        h[2] = (_Float16)v[2]; h[3] = (_Float16)v[3];
        *(half4*)&out[(size_t)i * 4] = h;
    }
}

__global__ void transmul2(const float* __restrict__ W, const float* __restrict__ J,
                          const float* __restrict__ Mk,
                          _Float16* __restrict__ effT, _Float16* __restrict__ JmT) {
    __shared__ float tw[32][33];
    __shared__ float tj[32][33];
    const int bx = blockIdx.x * 32, by = blockIdx.y * 32;
    const int tx = threadIdx.x, ty0 = threadIdx.y;
#pragma unroll
    for (int r = 0; r < 4; ++r) {
        int ty = ty0 + r * 8;
        size_t idx = (size_t)(by + ty) * NN + bx + tx;
        float mv = Mk[idx];
        tw[ty][tx] = W[idx] * mv;
        tj[ty][tx] = J[idx] * mv;
    }
    __syncthreads();
#pragma unroll
    for (int r = 0; r < 4; ++r) {
        int ty = ty0 + r * 8;
        size_t o = (size_t)(bx + ty) * NN + by + tx;
        effT[o] = (_Float16)tw[tx][ty];
        JmT[o]  = (_Float16)tj[tx][ty];
    }
}

__global__ void tsc_kernel(const float* __restrict__ theta, float* __restrict__ Tsc) {
    int i = blockIdx.x * blockDim.x + threadIdx.x;
    if (i < NN) Tsc[i] = fabsf(sinf(2.0f * theta[i])) * 0.1f;
}

__global__ void step_kernel(const float* __restrict__ signal, const float* __restrict__ sJ,
                            const float* __restrict__ noise, const float* __restrict__ Tsc,
                            const float* __restrict__ lamp,
                            _Float16* __restrict__ stateH, _Float16* __restrict__ sH) {
    const int i4 = blockIdx.x * blockDim.x + threadIdx.x;
    const float lam = lamp[0];
    const size_t base = (size_t)i4 * 4;
    f32x4 sg = *(const f32x4*)&signal[base];
    f32x4 dj = *(const f32x4*)&sJ[base];
    f32x4 nz = *(const f32x4*)&noise[base];
    const int col4 = (int)(base & (NN - 1));
    f32x4 tv = *(const f32x4*)&Tsc[col4];
    half4 so = *(const half4*)&sH[base];
    half4 hs, hn;
#pragma unroll
    for (int j = 0; j < 4; ++j) {
        float s = (float)so[j];
        float arg = sg[j] + lam * (dj[j] * s) + nz[j] * tv[j];
        float st = tanhf(arg);
        hs[j] = (_Float16)st;
        hn[j] = (_Float16)tanhf(st);
    }
    *(half4*)&stateH[base] = hs;
    *(half4*)&sH[base] = hn;
}

extern "C" void kernel_launch(void* const* d_in, const int* in_sizes, int n_in,
                              void* d_out, int out_size, void* d_ws, size_t ws_size,
                              hipStream_t stream) {
    const float* x       = (const float*)d_in[0];
    const float* W_in    = (const float*)d_in[1];
    const float* b_in    = (const float*)d_in[2];
    const float* weights = (const float*)d_in[3];
    const float* Jmat    = (const float*)d_in[4];
    const float* theta   = (const float*)d_in[5];
    const float* lam     = (const float*)d_in[6];
    const float* mask    = (const float*)d_in[7];
    const float* noise   = (const float*)d_in[8];
    const float* W_out   = (const float*)d_in[9];
    const float* b_out   = (const float*)d_in[10];
    float* out = (float*)d_out;

    char* w = (char*)d_ws;
    auto alloc = [&](size_t b) { char* p = w; w += (b + 255) & ~(size_t)255; return p; };
    _Float16* xh     = (_Float16*)alloc((size_t)TOKENS * IN_DIM * 2);
    _Float16* WinH   = (_Float16*)alloc((size_t)NN * IN_DIM * 2);
    _Float16* WoutH  = (_Float16*)alloc((size_t)OUT_DIM * NN * 2);
    _Float16* effT   = (_Float16*)alloc((size_t)NN * NN * 2);
    _Float16* JmT    = (_Float16*)alloc((size_t)NN * NN * 2);
    _Float16* stateH = (_Float16*)alloc((size_t)TOKENS * NN * 2);
    _Float16* sH     = (_Float16*)alloc((size_t)TOKENS * NN * 2);
    float* Tsc       = (float*)alloc((size_t)NN * 4);
    float* signal    = (float*)alloc((size_t)TOKENS * NN * 4);
    float* sJ        = (float*)alloc((size_t)TOKENS * NN * 4);

    cvt_f16<<<TOKENS * IN_DIM / 4 / 256, 256, 0, stream>>>(x, xh, TOKENS * IN_DIM / 4);
    cvt_f16<<<NN * IN_DIM / 4 / 256, 256, 0, stream>>>(W_in, WinH, NN * IN_DIM / 4);
    cvt_f16<<<OUT_DIM * NN / 4 / 256, 256, 0, stream>>>(W_out, WoutH, OUT_DIM * NN / 4);
    transmul2<<<dim3(NN / 32, NN / 32), dim3(32, 8), 0, stream>>>(weights, Jmat, mask, effT, JmT);
    tsc_kernel<<<NN / 256, 256, 0, stream>>>(theta, Tsc);

    // state = x @ W_in.T + b_in
    gemm_bt<1><<<dim3(NN / 128, TOKENS / 128), 256, 0, stream>>>(
        xh, WinH, nullptr, b_in, stateH, sH, TOKENS, NN, IN_DIM);

    for (int t = 0; t < TSTEPS; ++t) {
        dual_gemm<<<256, 512, 0, stream>>>(stateH, effT, signal, sH, JmT, sJ);
        step_kernel<<<TOKENS * NN / 4 / 256, 256, 0, stream>>>(
            signal, sJ, noise + (size_t)t * TOKENS * NN, Tsc, lam, stateH, sH);
    }

    // out = state @ W_out.T + b_out
    gemm_bt<2><<<dim3(OUT_DIM / 128, TOKENS / 128), 256, 0, stream>>>(
        stateH, WoutH, out, b_out, nullptr, nullptr, TOKENS, OUT_DIM, NN);
}

// Round 5
// 386.297 us; speedup vs baseline: 1.7298x; 1.0142x over previous
//
#include <hip/hip_runtime.h>
#include <hip/hip_fp16.h>

#define TOKENS 4096
#define NN 2048
#define IN_DIM 1024
#define OUT_DIM 1024
#define TSTEPS 3

typedef _Float16 half8 __attribute__((ext_vector_type(8)));
typedef _Float16 half4 __attribute__((ext_vector_type(4)));
typedef float f32x4 __attribute__((ext_vector_type(4)));

__device__ __forceinline__ void gload_lds16(const void* g, void* l) {
    __builtin_amdgcn_global_load_lds(
        (const __attribute__((address_space(1))) unsigned*)g,
        (__attribute__((address_space(3))) unsigned*)l, 16, 0, 0);
}

// ================= pipelined dual GEMM (recurrent step) =================
// 512 blocks x 256 threads (4 waves), tile 128x256, wave tile 128x64, BK=32.
// 2 blocks/CU (72 KiB LDS each) -> two independent barrier domains per CU:
// one block's MFMA bursts fill the other's lgkm/barrier stalls (m114 mechanism).
// 3-deep LDS ring, 2 tiles prefetch-ahead, counted vmcnt(6) (never 0 in
// steady state). XCD-chunked block swizzle for L2 locality.
// widx [0,256): C0 = A0 @ B0^T-layout; widx [256,512): C1 = A1 @ B1^T-layout.
__global__ __launch_bounds__(256, 2)
void dual_gemm(const _Float16* __restrict__ A0, const _Float16* __restrict__ B0,
               float* __restrict__ C0,
               const _Float16* __restrict__ A1, const _Float16* __restrict__ B1,
               float* __restrict__ C1)
{
    // 3 bufs x (A 128x32 + B 256x32) f16 = 3 x 24 KiB = 72 KiB
    __shared__ __align__(16) _Float16 lds[3 * 12288];
    const int tid  = threadIdx.x;
    const int wid  = tid >> 6;
    const int lane = tid & 63;

    // XCD-chunked swizzle: HW round-robins raw%8 across XCDs; give each XCD a
    // contiguous 64-item chunk (512 = 8*64, bijective).
    const int raw  = blockIdx.x;
    const int widx = (raw & 7) * 64 + (raw >> 3);
    const int g    = widx >> 8;
    const int bid  = widx & 255;
    const int by = bid >> 3;    // M/128 = 32 row tiles
    const int bx = bid & 7;     // N/256 = 8 col tiles
    const _Float16* __restrict__ A = g ? A1 : A0;
    const _Float16* __restrict__ B = g ? B1 : B0;
    float* __restrict__ C = g ? C1 : C0;
    const int brow = by << 7;
    const int bcol = bx << 8;

    // staging: one call = 256 thr x 16 B = 4 KiB = 64 rows x 64 B.
    // thread t: row = t>>2, phys col16 = t&3, fetch pre-swizzled logical
    // col16 = (t&3) ^ ((t>>3)&3)  (involution; row bits 1-2 = (t>>3)&3).
    const int sr = tid >> 2;
    const int sc = ((tid & 3) ^ ((tid >> 3) & 3)) << 3;
    const _Float16* gA = A + (size_t)(brow + sr) * NN + sc;
    const _Float16* gB = B + (size_t)(bcol + sr) * NN + sc;
    const int ldst = wid << 9;   // wave-uniform slice base within a call (f16)

    // buffer layout (f16 elems): A[128][32] at 0, B[256][32] at 4096; stride 12288.
    auto stageA = [&](int u, int b) {          // 2 calls
        _Float16* l = lds + b * 12288;
        const _Float16* a = gA + u * 32;
        gload_lds16(a,           l + ldst);
        gload_lds16(a + 64 * NN, l + 2048 + ldst);
    };
    auto stageB = [&](int u, int b) {          // 4 calls
        _Float16* l = lds + b * 12288 + 4096;
        const _Float16* p = gB + u * 32;
        gload_lds16(p,            l + ldst);
        gload_lds16(p + 64 * NN,  l + 2048 + ldst);
        gload_lds16(p + 128 * NN, l + 4096 + ldst);
        gload_lds16(p + 192 * NN, l + 6144 + ldst);
    };

    // read geometry: row R -> phys col16 = logical ^ ((R>>1)&3) = ^((lr>>1)&3).
    const int wc = wid << 6;          // 0/64/128/192 (waves split N)
    const int lr = lane & 15;
    const int swz = ((lane >> 4) ^ ((lr >> 1) & 3)) << 3;
    const int aRd = lr * 32 + swz;                 // + m*512, m = 0..7
    const int bRd = 4096 + (wc + lr) * 32 + swz;   // + n*512, n = 0..3

    f32x4 acc[8][4];
#pragma unroll
    for (int m = 0; m < 8; ++m)
#pragma unroll
        for (int n = 0; n < 4; ++n) acc[m][n] = (f32x4){0.f, 0.f, 0.f, 0.f};

    // prime: tiles 0,1 in flight (12 calls); wait tile 0 (6 younger outstanding)
    stageA(0, 0); stageB(0, 0);
    stageA(1, 1); stageB(1, 1);
    asm volatile("s_waitcnt vmcnt(6)" ::: "memory");
    __builtin_amdgcn_s_barrier();

    int cur = 0;
    for (int t = 0; t < 64; ++t) {
        const _Float16* lb = lds + cur * 12288;
        const int nb = (cur == 0) ? 2 : cur - 1;   // (cur+2)%3

        // ---------------- phase 1: m0-3 x n0-3 ----------------
        half8 af[4], bf[4];
#pragma unroll
        for (int m = 0; m < 4; ++m)
            af[m] = *(const half8*)&lb[aRd + (m << 9)];
#pragma unroll
        for (int n = 0; n < 4; ++n)
            bf[n] = *(const half8*)&lb[bRd + (n << 9)];
        if (t < 62) stageA(t + 2, nb);
        __builtin_amdgcn_s_barrier();
        asm volatile("s_waitcnt lgkmcnt(0)" ::: "memory");
        __builtin_amdgcn_sched_barrier(0);
        __builtin_amdgcn_s_setprio(1);
#pragma unroll
        for (int m = 0; m < 4; ++m)
#pragma unroll
            for (int n = 0; n < 4; ++n)
                acc[m][n] = __builtin_amdgcn_mfma_f32_16x16x32_f16(af[m], bf[n], acc[m][n], 0, 0, 0);
        __builtin_amdgcn_s_setprio(0);
        __builtin_amdgcn_sched_barrier(0);
        __builtin_amdgcn_s_barrier();

        // ---------------- phase 2: m4-7 x n0-3 (B regs reused) ----------------
#pragma unroll
        for (int m = 0; m < 4; ++m)
            af[m] = *(const half8*)&lb[aRd + ((m + 4) << 9)];
        if (t < 62) stageB(t + 2, nb);
        __builtin_amdgcn_s_barrier();
        asm volatile("s_waitcnt lgkmcnt(0)" ::: "memory");
        __builtin_amdgcn_sched_barrier(0);
        __builtin_amdgcn_s_setprio(1);
#pragma unroll
        for (int m = 0; m < 4; ++m)
#pragma unroll
            for (int n = 0; n < 4; ++n)
                acc[m + 4][n] = __builtin_amdgcn_mfma_f32_16x16x32_f16(af[m], bf[n], acc[m + 4][n], 0, 0, 0);
        __builtin_amdgcn_s_setprio(0);
        __builtin_amdgcn_sched_barrier(0);

        // prove tile t+1 resident before next iteration's reads issue
        if (t < 62)       asm volatile("s_waitcnt vmcnt(6)" ::: "memory");
        else if (t == 62) asm volatile("s_waitcnt vmcnt(0)" ::: "memory");
        __builtin_amdgcn_s_barrier();
        cur = (cur == 2) ? 0 : cur + 1;
    }

    // epilogue: C/D layout col=lane&15, row=(lane>>4)*4+j  [m89-verified]
    const int cr = (lane >> 4) << 2;
    const int cc = lane & 15;
#pragma unroll
    for (int m = 0; m < 8; ++m) {
#pragma unroll
        for (int n = 0; n < 4; ++n) {
            const size_t o0 = (size_t)(brow + m * 16 + cr) * NN
                            + (bcol + wc + n * 16 + cc);
#pragma unroll
            for (int j = 0; j < 4; ++j)
                C[o0 + (size_t)j * NN] = acc[m][n][j];
        }
    }
}

// ================= generic GEMM (input/output projections) =================
// EPI 1: v += bias; oSta = f16(v); oS = f16(tanh(v))
// EPI 2: C[o] = v + bias
template<int EPI>
__global__ __launch_bounds__(256)
void gemm_bt(const _Float16* __restrict__ A, const _Float16* __restrict__ B,
             float* __restrict__ C, const float* __restrict__ bias,
             _Float16* __restrict__ oSta, _Float16* __restrict__ oS,
             int M, int N, int K)
{
    __shared__ _Float16 As[128 * 32];
    __shared__ _Float16 Bs[128 * 32];
    const int tid  = threadIdx.x;
    const int wid  = tid >> 6;
    const int lane = tid & 63;
    const int wr = (wid >> 1) * 64;
    const int wc = (wid & 1) * 64;
    const int brow = blockIdx.y * 128;
    const int bcol = blockIdx.x * 128;

    f32x4 acc[4][4];
#pragma unroll
    for (int m = 0; m < 4; ++m)
#pragma unroll
        for (int n = 0; n < 4; ++n) acc[m][n] = (f32x4){0.f, 0.f, 0.f, 0.f};

    const int ldr = tid >> 2;
    const int ldc = (tid & 3) * 8;
    const int wbase = (wid << 4) * 32;
    const int kq = (lane >> 4) * 8;
    const int lr = lane & 15;

    for (int k0 = 0; k0 < K; k0 += 32) {
        __syncthreads();
        gload_lds16(A + (size_t)(brow + ldr) * K + k0 + ldc, As + wbase);
        gload_lds16(A + (size_t)(brow + 64 + ldr) * K + k0 + ldc, As + 64 * 32 + wbase);
        gload_lds16(B + (size_t)(bcol + ldr) * K + k0 + ldc, Bs + wbase);
        gload_lds16(B + (size_t)(bcol + 64 + ldr) * K + k0 + ldc, Bs + 64 * 32 + wbase);
        __syncthreads();

        half8 af[4], bf[4];
#pragma unroll
        for (int m = 0; m < 4; ++m)
            af[m] = *(const half8*)&As[(wr + m * 16 + lr) * 32 + kq];
#pragma unroll
        for (int n = 0; n < 4; ++n)
            bf[n] = *(const half8*)&Bs[(wc + n * 16 + lr) * 32 + kq];
#pragma unroll
        for (int m = 0; m < 4; ++m)
#pragma unroll
            for (int n = 0; n < 4; ++n)
                acc[m][n] = __builtin_amdgcn_mfma_f32_16x16x32_f16(af[m], bf[n], acc[m][n], 0, 0, 0);
    }

    const int cr = (lane >> 4) * 4;
    const int cc = lane & 15;
#pragma unroll
    for (int m = 0; m < 4; ++m) {
#pragma unroll
        for (int n = 0; n < 4; ++n) {
            const int ccol = bcol + wc + n * 16 + cc;
#pragma unroll
            for (int j = 0; j < 4; ++j) {
                const int crow = brow + wr + m * 16 + cr + j;
                float v = acc[m][n][j];
                const size_t o = (size_t)crow * N + ccol;
                if (EPI == 1) {
                    v += bias[ccol];
                    oSta[o] = (_Float16)v;
                    oS[o] = (_Float16)tanhf(v);
                } else {
                    C[o] = v + bias[ccol];
                }
            }
        }
    }
}

// ================= small prep / elementwise kernels =================
__global__ void cvt_f16(const float* __restrict__ in, _Float16* __restrict__ out, int n4) {
    int i = blockIdx.x * blockDim.x + threadIdx.x;
    if (i < n4) {
        f32x4 v = *(const f32x4*)&in[(size_t)i * 4];
        half4 h;
        h[0] = (_Float16)v[0]; h[1] = (_Float16)v[1];
        h[2] = (_Float16)v[2]; h[3] = (_Float16)v[3];
        *(half4*)&out[(size_t)i * 4] = h;
    }
}

__global__ void transmul2(const float* __restrict__ W, const float* __restrict__ J,
                          const float* __restrict__ Mk,
                          _Float16* __restrict__ effT, _Float16* __restrict__ JmT) {
    __shared__ float tw[32][33];
    __shared__ float tj[32][33];
    const int bx = blockIdx.x * 32, by = blockIdx.y * 32;
    const int tx = threadIdx.x, ty0 = threadIdx.y;
#pragma unroll
    for (int r = 0; r < 4; ++r) {
        int ty = ty0 + r * 8;
        size_t idx = (size_t)(by + ty) * NN + bx + tx;
        float mv = Mk[idx];
        tw[ty][tx] = W[idx] * mv;
        tj[ty][tx] = J[idx] * mv;
    }
    __syncthreads();
#pragma unroll
    for (int r = 0; r < 4; ++r) {
        int ty = ty0 + r * 8;
        size_t o = (size_t)(bx + ty) * NN + by + tx;
        effT[o] = (_Float16)tw[tx][ty];
        JmT[o]  = (_Float16)tj[tx][ty];
    }
}

__global__ void tsc_kernel(const float* __restrict__ theta, float* __restrict__ Tsc) {
    int i = blockIdx.x * blockDim.x + threadIdx.x;
    if (i < NN) Tsc[i] = fabsf(sinf(2.0f * theta[i])) * 0.1f;
}

__global__ void step_kernel(const float* __restrict__ signal, const float* __restrict__ sJ,
                            const float* __restrict__ noise, const float* __restrict__ Tsc,
                            const float* __restrict__ lamp,
                            _Float16* __restrict__ stateH, _Float16* __restrict__ sH) {
    const int i4 = blockIdx.x * blockDim.x + threadIdx.x;
    const float lam = lamp[0];
    const size_t base = (size_t)i4 * 4;
    f32x4 sg = *(const f32x4*)&signal[base];
    f32x4 dj = *(const f32x4*)&sJ[base];
    f32x4 nz = *(const f32x4*)&noise[base];
    const int col4 = (int)(base & (NN - 1));
    f32x4 tv = *(const f32x4*)&Tsc[col4];
    half4 so = *(const half4*)&sH[base];
    half4 hs, hn;
#pragma unroll
    for (int j = 0; j < 4; ++j) {
        float s = (float)so[j];
        float arg = sg[j] + lam * (dj[j] * s) + nz[j] * tv[j];
        float st = tanhf(arg);
        hs[j] = (_Float16)st;
        hn[j] = (_Float16)tanhf(st);
    }
    *(half4*)&stateH[base] = hs;
    *(half4*)&sH[base] = hn;
}

extern "C" void kernel_launch(void* const* d_in, const int* in_sizes, int n_in,
                              void* d_out, int out_size, void* d_ws, size_t ws_size,
                              hipStream_t stream) {
    const float* x       = (const float*)d_in[0];
    const float* W_in    = (const float*)d_in[1];
    const float* b_in    = (const float*)d_in[2];
    const float* weights = (const float*)d_in[3];
    const float* Jmat    = (const float*)d_in[4];
    const float* theta   = (const float*)d_in[5];
    const float* lam     = (const float*)d_in[6];
    const float* mask    = (const float*)d_in[7];
    const float* noise   = (const float*)d_in[8];
    const float* W_out   = (const float*)d_in[9];
    const float* b_out   = (const float*)d_in[10];
    float* out = (float*)d_out;

    char* w = (char*)d_ws;
    auto alloc = [&](size_t b) { char* p = w; w += (b + 255) & ~(size_t)255; return p; };
    _Float16* xh     = (_Float16*)alloc((size_t)TOKENS * IN_DIM * 2);
    _Float16* WinH   = (_Float16*)alloc((size_t)NN * IN_DIM * 2);
    _Float16* WoutH  = (_Float16*)alloc((size_t)OUT_DIM * NN * 2);
    _Float16* effT   = (_Float16*)alloc((size_t)NN * NN * 2);
    _Float16* JmT    = (_Float16*)alloc((size_t)NN * NN * 2);
    _Float16* stateH = (_Float16*)alloc((size_t)TOKENS * NN * 2);
    _Float16* sH     = (_Float16*)alloc((size_t)TOKENS * NN * 2);
    float* Tsc       = (float*)alloc((size_t)NN * 4);
    float* signal    = (float*)alloc((size_t)TOKENS * NN * 4);
    float* sJ        = (float*)alloc((size_t)TOKENS * NN * 4);

    cvt_f16<<<TOKENS * IN_DIM / 4 / 256, 256, 0, stream>>>(x, xh, TOKENS * IN_DIM / 4);
    cvt_f16<<<NN * IN_DIM / 4 / 256, 256, 0, stream>>>(W_in, WinH, NN * IN_DIM / 4);
    cvt_f16<<<OUT_DIM * NN / 4 / 256, 256, 0, stream>>>(W_out, WoutH, OUT_DIM * NN / 4);
    transmul2<<<dim3(NN / 32, NN / 32), dim3(32, 8), 0, stream>>>(weights, Jmat, mask, effT, JmT);
    tsc_kernel<<<NN / 256, 256, 0, stream>>>(theta, Tsc);

    // state = x @ W_in.T + b_in
    gemm_bt<1><<<dim3(NN / 128, TOKENS / 128), 256, 0, stream>>>(
        xh, WinH, nullptr, b_in, stateH, sH, TOKENS, NN, IN_DIM);

    for (int t = 0; t < TSTEPS; ++t) {
        dual_gemm<<<512, 256, 0, stream>>>(stateH, effT, signal, sH, JmT, sJ);
        step_kernel<<<TOKENS * NN / 4 / 256, 256, 0, stream>>>(
            signal, sJ, noise + (size_t)t * TOKENS * NN, Tsc, lam, stateH, sH);
    }

    // out = state @ W_out.T + b_out
    gemm_bt<2><<<dim3(OUT_DIM / 128, TOKENS / 128), 256, 0, stream>>>(
        stateH, WoutH, out, b_out, nullptr, nullptr, TOKENS, OUT_DIM, NN);
}

// Round 7
// 381.289 us; speedup vs baseline: 1.7525x; 1.0131x over previous
//
#include <hip/hip_runtime.h>
#include <hip/hip_fp16.h>

#define TOKENS 4096
#define NN 2048
#define IN_DIM 1024
#define OUT_DIM 1024
#define TSTEPS 3

typedef _Float16 half8 __attribute__((ext_vector_type(8)));
typedef _Float16 half4 __attribute__((ext_vector_type(4)));
typedef float f32x4 __attribute__((ext_vector_type(4)));

__device__ __forceinline__ void gload_lds16(const void* g, void* l) {
    __builtin_amdgcn_global_load_lds(
        (const __attribute__((address_space(1))) unsigned*)g,
        (__attribute__((address_space(3))) unsigned*)l, 16, 0, 0);
}

// ================= 8-phase dual GEMM (recurrent step) =================
// 256 blocks x 512 threads (8 waves), tile 256x256, BK=64, wave tile 128x64.
// LDS 128 KiB: 2 bufs x {A[256][64] | B[256][64]} f16, rows XOR-swizzled
// (phys 16B-chunk = logical ^ (row&7)); staged via pre-swizzled global src.
// Ledger (conservative, full-tile): B(T+2) staged at q2 (B fully read by q1),
// A(T+2) staged at q3 (A fully read by q2); single vmcnt(8) at q3-end proves
// ALL of tile T+1 resident (only T+2's 8 calls remain outstanding).
// Blocks [0,128): C0 = A0 @ B0^T-layout; [128,256): C1 = A1 @ B1^T-layout.
__global__ __launch_bounds__(512, 2)
void dual_gemm(const _Float16* __restrict__ A0g, const _Float16* __restrict__ B0g,
               float* __restrict__ C0,
               const _Float16* __restrict__ A1g, const _Float16* __restrict__ B1g,
               float* __restrict__ C1)
{
    __shared__ __align__(16) _Float16 lds[2 * 32768];   // 128 KiB
    const int tid  = threadIdx.x;
    const int wid  = tid >> 6;
    const int lane = tid & 63;

    // XCD-chunked swizzle: 256 = 8 * 32, bijective
    const int raw  = blockIdx.x;
    const int widx = (raw & 7) * 32 + (raw >> 3);
    const int g    = widx >> 7;
    const int bid  = widx & 127;
    const int by = bid >> 3;    // M/256 = 16
    const int bx = bid & 7;     // N/256 = 8
    const _Float16* __restrict__ A = g ? A1g : A0g;
    const _Float16* __restrict__ B = g ? B1g : B0g;
    float* __restrict__ C = g ? C1 : C0;
    const int brow = by << 8;
    const int bcol = bx << 8;

    // staging: one call = 512 thr x 16 B = 8 KB = 64 rows x 64 f16.
    // thread t: row = t>>3, phys chunk = t&7; fetch logical chunk (t&7)^(row&7).
    const int sr = tid >> 3;
    const int sc = ((tid & 7) ^ (sr & 7)) << 3;
    const _Float16* gA = A + (size_t)(brow + sr) * NN + sc;
    const _Float16* gB = B + (size_t)(bcol + sr) * NN + sc;
    const int ldst = wid << 9;   // wave-uniform slice base (8 rows x 64 f16)

    // half-tile stagers: h in {0,1} = 128-row block; tile T -> buffer T&1
    auto stA = [&](int T, int h) {
        _Float16* l = lds + (T & 1) * 32768 + h * 8192;
        const _Float16* p = gA + (size_t)(h << 7) * NN + (T << 6);
        gload_lds16(p,           l + ldst);
        gload_lds16(p + 64 * NN, l + 4096 + ldst);
    };
    auto stB = [&](int T, int h) {
        _Float16* l = lds + (T & 1) * 32768 + 16384 + h * 8192;
        const _Float16* p = gB + (size_t)(h << 7) * NN + (T << 6);
        gload_lds16(p,           l + ldst);
        gload_lds16(p + 64 * NN, l + 4096 + ldst);
    };

    // read geometry: frag f16 idx = row*64 + (chunk ^ (row&7))*8, chunk = kk*4 + lq
    const int wr = (wid >> 2) << 7;   // 0 / 128
    const int wc = (wid & 3) << 6;    // 0 / 64 / 128 / 192
    const int lr = lane & 15;
    const int lq = lane >> 4;
    const int x7 = lr & 7;            // row&7 == lr&7 (wr, m*16, wc, n*16 all %8==0)
    const int c0 = (lq ^ x7) << 3;
    const int c1 = ((4 + lq) ^ x7) << 3;
    const int aRow = (wr + lr) << 6;             // + m*1024
    const int bRow = 16384 + ((wc + lr) << 6);   // + n*1024

    f32x4 acc[8][4];
#pragma unroll
    for (int m = 0; m < 8; ++m)
#pragma unroll
        for (int n = 0; n < 4; ++n) acc[m][n] = (f32x4){0.f, 0.f, 0.f, 0.f};

    half8 af[4][2], b0f[2][2], b1f[2][2];

    // prologue: stage tiles 0,1 (16 calls); vmcnt(8) proves ALL of tile 0 done.
    stA(0, 0); stA(0, 1); stB(0, 0); stB(0, 1);
    stA(1, 0); stA(1, 1); stB(1, 0); stB(1, 1);
    asm volatile("s_waitcnt vmcnt(8)" ::: "memory");
    __builtin_amdgcn_s_barrier();
    asm volatile("" ::: "memory");

    for (int T = 0; T < 32; ++T) {
        const _Float16* lb = lds + (T & 1) * 32768;

        // ======== q0: read A rows wr..wr+63 (m0-3) + B n0-1; MFMA m0-3 x n0-1
#pragma unroll
        for (int m = 0; m < 4; ++m) {
            af[m][0] = *(const half8*)&lb[aRow + (m << 10) + c0];
            af[m][1] = *(const half8*)&lb[aRow + (m << 10) + c1];
        }
#pragma unroll
        for (int n = 0; n < 2; ++n) {
            b0f[n][0] = *(const half8*)&lb[bRow + (n << 10) + c0];
            b0f[n][1] = *(const half8*)&lb[bRow + (n << 10) + c1];
        }
        __builtin_amdgcn_s_barrier();
        asm volatile("s_waitcnt lgkmcnt(0)" ::: "memory");
        __builtin_amdgcn_sched_barrier(0);
        __builtin_amdgcn_s_setprio(1);
#pragma unroll
        for (int kk = 0; kk < 2; ++kk)
#pragma unroll
            for (int m = 0; m < 4; ++m)
#pragma unroll
                for (int n = 0; n < 2; ++n)
                    acc[m][n] = __builtin_amdgcn_mfma_f32_16x16x32_f16(af[m][kk], b0f[n][kk], acc[m][n], 0, 0, 0);
        __builtin_amdgcn_s_setprio(0);
        __builtin_amdgcn_sched_barrier(0);
        __builtin_amdgcn_s_barrier();
        asm volatile("" ::: "memory");

        // ======== q1: read B n2-3; MFMA m0-3 x n2-3   (B fully read after this)
#pragma unroll
        for (int n = 0; n < 2; ++n) {
            b1f[n][0] = *(const half8*)&lb[bRow + ((n + 2) << 10) + c0];
            b1f[n][1] = *(const half8*)&lb[bRow + ((n + 2) << 10) + c1];
        }
        __builtin_amdgcn_s_barrier();
        asm volatile("s_waitcnt lgkmcnt(0)" ::: "memory");
        __builtin_amdgcn_sched_barrier(0);
        __builtin_amdgcn_s_setprio(1);
#pragma unroll
        for (int kk = 0; kk < 2; ++kk)
#pragma unroll
            for (int m = 0; m < 4; ++m)
#pragma unroll
                for (int n = 0; n < 2; ++n)
                    acc[m][n + 2] = __builtin_amdgcn_mfma_f32_16x16x32_f16(af[m][kk], b1f[n][kk], acc[m][n + 2], 0, 0, 0);
        __builtin_amdgcn_s_setprio(0);
        __builtin_amdgcn_sched_barrier(0);
        __builtin_amdgcn_s_barrier();
        asm volatile("" ::: "memory");

        // ======== q2: read A rows wr+64..wr+127 (m4-7); stage B(T+2) (safe:
        // all B reads of tile T done at q1-end barrier); MFMA m4-7 x n0-1
#pragma unroll
        for (int m = 0; m < 4; ++m) {
            af[m][0] = *(const half8*)&lb[aRow + ((m + 4) << 10) + c0];
            af[m][1] = *(const half8*)&lb[aRow + ((m + 4) << 10) + c1];
        }
        if (T < 30) { stB(T + 2, 0); stB(T + 2, 1); }
        __builtin_amdgcn_s_barrier();
        asm volatile("s_waitcnt lgkmcnt(0)" ::: "memory");
        __builtin_amdgcn_sched_barrier(0);
        __builtin_amdgcn_s_setprio(1);
#pragma unroll
        for (int kk = 0; kk < 2; ++kk)
#pragma unroll
            for (int m = 0; m < 4; ++m)
#pragma unroll
                for (int n = 0; n < 2; ++n)
                    acc[m + 4][n] = __builtin_amdgcn_mfma_f32_16x16x32_f16(af[m][kk], b0f[n][kk], acc[m + 4][n], 0, 0, 0);
        __builtin_amdgcn_s_setprio(0);
        __builtin_amdgcn_sched_barrier(0);
        __builtin_amdgcn_s_barrier();
        asm volatile("" ::: "memory");

        // ======== q3: stage A(T+2) (safe: all A reads of tile T done at
        // q2-end barrier); MFMA m4-7 x n2-3 (registers only)
        if (T < 30) { stA(T + 2, 0); stA(T + 2, 1); }
        __builtin_amdgcn_s_setprio(1);
#pragma unroll
        for (int kk = 0; kk < 2; ++kk)
#pragma unroll
            for (int m = 0; m < 4; ++m)
#pragma unroll
                for (int n = 0; n < 2; ++n)
                    acc[m + 4][n + 2] = __builtin_amdgcn_mfma_f32_16x16x32_f16(af[m][kk], b1f[n][kk], acc[m + 4][n + 2], 0, 0, 0);
        __builtin_amdgcn_s_setprio(0);
        __builtin_amdgcn_sched_barrier(0);
        // retire ALL of tile T+1 (8 oldest); only T+2's 8 calls stay in flight
        if (T < 30)       asm volatile("s_waitcnt vmcnt(8)" ::: "memory");
        else if (T == 30) asm volatile("s_waitcnt vmcnt(0)" ::: "memory");
        __builtin_amdgcn_s_barrier();
        asm volatile("" ::: "memory");
    }

    // epilogue: C/D layout col=lane&15, row=(lane>>4)*4+j  [m89-verified]
    const int cr = lq << 2;
    const int cc = lane & 15;
#pragma unroll
    for (int m = 0; m < 8; ++m) {
#pragma unroll
        for (int n = 0; n < 4; ++n) {
            const size_t o0 = (size_t)(brow + wr + m * 16 + cr) * NN
                            + (bcol + wc + n * 16 + cc);
#pragma unroll
            for (int j = 0; j < 4; ++j)
                C[o0 + (size_t)j * NN] = acc[m][n][j];
        }
    }
}

// ================= generic GEMM (input/output projections) =================
// EPI 1: v += bias; oSta = f16(v); oS = f16(tanh(v))
// EPI 2: C[o] = v + bias
template<int EPI>
__global__ __launch_bounds__(256)
void gemm_bt(const _Float16* __restrict__ A, const _Float16* __restrict__ B,
             float* __restrict__ C, const float* __restrict__ bias,
             _Float16* __restrict__ oSta, _Float16* __restrict__ oS,
             int M, int N, int K)
{
    __shared__ _Float16 As[128 * 32];
    __shared__ _Float16 Bs[128 * 32];
    const int tid  = threadIdx.x;
    const int wid  = tid >> 6;
    const int lane = tid & 63;
    const int wr = (wid >> 1) * 64;
    const int wc = (wid & 1) * 64;
    const int brow = blockIdx.y * 128;
    const int bcol = blockIdx.x * 128;

    f32x4 acc[4][4];
#pragma unroll
    for (int m = 0; m < 4; ++m)
#pragma unroll
        for (int n = 0; n < 4; ++n) acc[m][n] = (f32x4){0.f, 0.f, 0.f, 0.f};

    const int ldr = tid >> 2;
    const int ldc = (tid & 3) * 8;
    const int wbase = (wid << 4) * 32;
    const int kq = (lane >> 4) * 8;
    const int lr = lane & 15;

    for (int k0 = 0; k0 < K; k0 += 32) {
        __syncthreads();
        gload_lds16(A + (size_t)(brow + ldr) * K + k0 + ldc, As + wbase);
        gload_lds16(A + (size_t)(brow + 64 + ldr) * K + k0 + ldc, As + 64 * 32 + wbase);
        gload_lds16(B + (size_t)(bcol + ldr) * K + k0 + ldc, Bs + wbase);
        gload_lds16(B + (size_t)(bcol + 64 + ldr) * K + k0 + ldc, Bs + 64 * 32 + wbase);
        __syncthreads();

        half8 af[4], bf[4];
#pragma unroll
        for (int m = 0; m < 4; ++m)
            af[m] = *(const half8*)&As[(wr + m * 16 + lr) * 32 + kq];
#pragma unroll
        for (int n = 0; n < 4; ++n)
            bf[n] = *(const half8*)&Bs[(wc + n * 16 + lr) * 32 + kq];
#pragma unroll
        for (int m = 0; m < 4; ++m)
#pragma unroll
            for (int n = 0; n < 4; ++n)
                acc[m][n] = __builtin_amdgcn_mfma_f32_16x16x32_f16(af[m], bf[n], acc[m][n], 0, 0, 0);
    }

    const int cr = (lane >> 4) * 4;
    const int cc = lane & 15;
#pragma unroll
    for (int m = 0; m < 4; ++m) {
#pragma unroll
        for (int n = 0; n < 4; ++n) {
            const int ccol = bcol + wc + n * 16 + cc;
#pragma unroll
            for (int j = 0; j < 4; ++j) {
                const int crow = brow + wr + m * 16 + cr + j;
                float v = acc[m][n][j];
                const size_t o = (size_t)crow * N + ccol;
                if (EPI == 1) {
                    v += bias[ccol];
                    oSta[o] = (_Float16)v;
                    oS[o] = (_Float16)tanhf(v);
                } else {
                    C[o] = v + bias[ccol];
                }
            }
        }
    }
}

// ================= small prep / elementwise kernels =================
__global__ void cvt_f16(const float* __restrict__ in, _Float16* __restrict__ out, int n4) {
    int i = blockIdx.x * blockDim.x + threadIdx.x;
    if (i < n4) {
        f32x4 v = *(const f32x4*)&in[(size_t)i * 4];
        half4 h;
        h[0] = (_Float16)v[0]; h[1] = (_Float16)v[1];
        h[2] = (_Float16)v[2]; h[3] = (_Float16)v[3];
        *(half4*)&out[(size_t)i * 4] = h;
    }
}

__global__ void transmul2(const float* __restrict__ W, const float* __restrict__ J,
                          const float* __restrict__ Mk,
                          _Float16* __restrict__ effT, _Float16* __restrict__ JmT) {
    __shared__ float tw[32][33];
    __shared__ float tj[32][33];
    const int bx = blockIdx.x * 32, by = blockIdx.y * 32;
    const int tx = threadIdx.x, ty0 = threadIdx.y;
#pragma unroll
    for (int r = 0; r < 4; ++r) {
        int ty = ty0 + r * 8;
        size_t idx = (size_t)(by + ty) * NN + bx + tx;
        float mv = Mk[idx];
        tw[ty][tx] = W[idx] * mv;
        tj[ty][tx] = J[idx] * mv;
    }
    __syncthreads();
#pragma unroll
    for (int r = 0; r < 4; ++r) {
        int ty = ty0 + r * 8;
        size_t o = (size_t)(bx + ty) * NN + by + tx;
        effT[o] = (_Float16)tw[tx][ty];
        JmT[o]  = (_Float16)tj[tx][ty];
    }
}

__global__ void tsc_kernel(const float* __restrict__ theta, float* __restrict__ Tsc) {
    int i = blockIdx.x * blockDim.x + threadIdx.x;
    if (i < NN) Tsc[i] = fabsf(sinf(2.0f * theta[i])) * 0.1f;
}

__global__ void step_kernel(const float* __restrict__ signal, const float* __restrict__ sJ,
                            const float* __restrict__ noise, const float* __restrict__ Tsc,
                            const float* __restrict__ lamp,
                            _Float16* __restrict__ stateH, _Float16* __restrict__ sH) {
    const int i4 = blockIdx.x * blockDim.x + threadIdx.x;
    const float lam = lamp[0];
    const size_t base = (size_t)i4 * 4;
    f32x4 sg = *(const f32x4*)&signal[base];
    f32x4 dj = *(const f32x4*)&sJ[base];
    f32x4 nz = *(const f32x4*)&noise[base];
    const int col4 = (int)(base & (NN - 1));
    f32x4 tv = *(const f32x4*)&Tsc[col4];
    half4 so = *(const half4*)&sH[base];
    half4 hs, hn;
#pragma unroll
    for (int j = 0; j < 4; ++j) {
        float s = (float)so[j];
        float arg = sg[j] + lam * (dj[j] * s) + nz[j] * tv[j];
        float st = tanhf(arg);
        hs[j] = (_Float16)st;
        hn[j] = (_Float16)tanhf(st);
    }
    *(half4*)&stateH[base] = hs;
    *(half4*)&sH[base] = hn;
}

extern "C" void kernel_launch(void* const* d_in, const int* in_sizes, int n_in,
                              void* d_out, int out_size, void* d_ws, size_t ws_size,
                              hipStream_t stream) {
    const float* x       = (const float*)d_in[0];
    const float* W_in    = (const float*)d_in[1];
    const float* b_in    = (const float*)d_in[2];
    const float* weights = (const float*)d_in[3];
    const float* Jmat    = (const float*)d_in[4];
    const float* theta   = (const float*)d_in[5];
    const float* lam     = (const float*)d_in[6];
    const float* mask    = (const float*)d_in[7];
    const float* noise   = (const float*)d_in[8];
    const float* W_out   = (const float*)d_in[9];
    const float* b_out   = (const float*)d_in[10];
    float* out = (float*)d_out;

    char* w = (char*)d_ws;
    auto alloc = [&](size_t b) { char* p = w; w += (b + 255) & ~(size_t)255; return p; };
    _Float16* xh     = (_Float16*)alloc((size_t)TOKENS * IN_DIM * 2);
    _Float16* WinH   = (_Float16*)alloc((size_t)NN * IN_DIM * 2);
    _Float16* WoutH  = (_Float16*)alloc((size_t)OUT_DIM * NN * 2);
    _Float16* effT   = (_Float16*)alloc((size_t)NN * NN * 2);
    _Float16* JmT    = (_Float16*)alloc((size_t)NN * NN * 2);
    _Float16* stateH = (_Float16*)alloc((size_t)TOKENS * NN * 2);
    _Float16* sH     = (_Float16*)alloc((size_t)TOKENS * NN * 2);
    float* Tsc       = (float*)alloc((size_t)NN * 4);
    float* signal    = (float*)alloc((size_t)TOKENS * NN * 4);
    float* sJ        = (float*)alloc((size_t)TOKENS * NN * 4);

    cvt_f16<<<TOKENS * IN_DIM / 4 / 256, 256, 0, stream>>>(x, xh, TOKENS * IN_DIM / 4);
    cvt_f16<<<NN * IN_DIM / 4 / 256, 256, 0, stream>>>(W_in, WinH, NN * IN_DIM / 4);
    cvt_f16<<<OUT_DIM * NN / 4 / 256, 256, 0, stream>>>(W_out, WoutH, OUT_DIM * NN / 4);
    transmul2<<<dim3(NN / 32, NN / 32), dim3(32, 8), 0, stream>>>(weights, Jmat, mask, effT, JmT);
    tsc_kernel<<<NN / 256, 256, 0, stream>>>(theta, Tsc);

    // state = x @ W_in.T + b_in
    gemm_bt<1><<<dim3(NN / 128, TOKENS / 128), 256, 0, stream>>>(
        xh, WinH, nullptr, b_in, stateH, sH, TOKENS, NN, IN_DIM);

    for (int t = 0; t < TSTEPS; ++t) {
        dual_gemm<<<256, 512, 0, stream>>>(stateH, effT, signal, sH, JmT, sJ);
        step_kernel<<<TOKENS * NN / 4 / 256, 256, 0, stream>>>(
            signal, sJ, noise + (size_t)t * TOKENS * NN, Tsc, lam, stateH, sH);
    }

    // out = state @ W_out.T + b_out
    gemm_bt<2><<<dim3(OUT_DIM / 128, TOKENS / 128), 256, 0, stream>>>(
        stateH, WoutH, out, b_out, nullptr, nullptr, TOKENS, OUT_DIM, NN);
}

// Round 8
// 370.386 us; speedup vs baseline: 1.8041x; 1.0294x over previous
//
#include <hip/hip_runtime.h>
#include <hip/hip_fp16.h>

#define TOKENS 4096
#define NN 2048
#define IN_DIM 1024
#define OUT_DIM 1024
#define TSTEPS 3

typedef _Float16 half8 __attribute__((ext_vector_type(8)));
typedef _Float16 half4 __attribute__((ext_vector_type(4)));
typedef float f32x4 __attribute__((ext_vector_type(4)));

__device__ __forceinline__ void gload_lds16(const void* g, void* l) {
    __builtin_amdgcn_global_load_lds(
        (const __attribute__((address_space(1))) unsigned*)g,
        (__attribute__((address_space(3))) unsigned*)l, 16, 0, 0);
}

#define LGKM(N) asm volatile("s_waitcnt lgkmcnt(" #N ")" ::: "memory")
#define VMCNT(N) asm volatile("s_waitcnt vmcnt(" #N ")" ::: "memory")
#define SCHED0() __builtin_amdgcn_sched_barrier(0)

// ================= pipelined dual GEMM (recurrent step) =================
// 256 blocks x 512 threads (8 waves), tile 256x256, BK=64, wave tile 128x64.
// LDS 128 KiB: 2 bufs x {A[256][64] | B[256][64]} f16, rows XOR-swizzled.
// Software-pipelined reads: 4 MFMA groups/K-tile; group g+1's ds_reads are
// issued BEFORE group g's MFMAs with COUNTED lgkmcnt waits (4/8/4/0), so the
// LDS pipe streams under the MFMA bursts. Only 2 barriers per K-tile:
//  #1 after lgkm(0): all waves done reading tile T (stage T+2 may overwrite)
//  #2 after vmcnt(8) post-stage: tile T+1 resident block-wide (reads may start)
// Blocks [0,128): C0 = A0 @ B0^T-layout; [128,256): C1 = A1 @ B1^T-layout.
__global__ __launch_bounds__(512, 2)
void dual_gemm(const _Float16* __restrict__ A0g, const _Float16* __restrict__ B0g,
               float* __restrict__ C0,
               const _Float16* __restrict__ A1g, const _Float16* __restrict__ B1g,
               float* __restrict__ C1)
{
    __shared__ __align__(16) _Float16 lds[2 * 32768];   // 128 KiB
    const int tid  = threadIdx.x;
    const int wid  = tid >> 6;
    const int lane = tid & 63;

    // XCD-chunked swizzle: 256 = 8 * 32, bijective
    const int raw  = blockIdx.x;
    const int widx = (raw & 7) * 32 + (raw >> 3);
    const int g    = widx >> 7;
    const int bid  = widx & 127;
    const int by = bid >> 3;    // M/256 = 16
    const int bx = bid & 7;     // N/256 = 8
    const _Float16* __restrict__ A = g ? A1g : A0g;
    const _Float16* __restrict__ B = g ? B1g : B0g;
    float* __restrict__ C = g ? C1 : C0;
    const int brow = by << 8;
    const int bcol = bx << 8;

    // staging: one call = 512 thr x 16 B = 8 KB = 64 rows x 64 f16.
    // thread t: row = t>>3, phys chunk = t&7; fetch logical chunk (t&7)^(row&7).
    const int sr = tid >> 3;
    const int sc = ((tid & 7) ^ (sr & 7)) << 3;
    const _Float16* gA = A + (size_t)(brow + sr) * NN + sc;
    const _Float16* gB = B + (size_t)(bcol + sr) * NN + sc;
    const int ldst = wid << 9;   // wave-uniform slice base (8 rows x 64 f16)

    auto stA = [&](int T, int h) {
        _Float16* l = lds + (T & 1) * 32768 + h * 8192;
        const _Float16* p = gA + (size_t)(h << 7) * NN + (T << 6);
        gload_lds16(p,           l + ldst);
        gload_lds16(p + 64 * NN, l + 4096 + ldst);
    };
    auto stB = [&](int T, int h) {
        _Float16* l = lds + (T & 1) * 32768 + 16384 + h * 8192;
        const _Float16* p = gB + (size_t)(h << 7) * NN + (T << 6);
        gload_lds16(p,           l + ldst);
        gload_lds16(p + 64 * NN, l + 4096 + ldst);
    };

    // read geometry: frag f16 idx = row*64 + (chunk ^ (row&7))*8, chunk = kk*4 + lq
    const int wr = (wid >> 2) << 7;   // 0 / 128
    const int wc = (wid & 3) << 6;    // 0 / 64 / 128 / 192
    const int lr = lane & 15;
    const int lq = lane >> 4;
    const int x7 = lr & 7;            // row&7 == lr&7 (wr, m*16, wc, n*16 all %8==0)
    const int c0 = (lq ^ x7) << 3;
    const int c1 = ((4 + lq) ^ x7) << 3;
    const int aRow = (wr + lr) << 6;             // + m*1024
    const int bRow = 16384 + ((wc + lr) << 6);   // + n*1024

    f32x4 acc[8][4];
#pragma unroll
    for (int m = 0; m < 8; ++m)
#pragma unroll
        for (int n = 0; n < 4; ++n) acc[m][n] = (f32x4){0.f, 0.f, 0.f, 0.f};

    half8 af0[4], af1[4], af2[4], af3[4], bf0[4], bf1[4];

    // prologue: stage tiles 0,1 (16 calls); vmcnt(8) proves tile 0 done
    stA(0, 0); stA(0, 1); stB(0, 0); stB(0, 1);
    stA(1, 0); stA(1, 1); stB(1, 0); stB(1, 1);
    VMCNT(8);
    __builtin_amdgcn_s_barrier();
    {   // issue g0 reads of tile 0 (8): A m0-3 kk0, B n0-3 kk0
        const _Float16* lb = lds;
#pragma unroll
        for (int m = 0; m < 4; ++m) af0[m] = *(const half8*)&lb[aRow + (m << 10) + c0];
#pragma unroll
        for (int n = 0; n < 4; ++n) bf0[n] = *(const half8*)&lb[bRow + (n << 10) + c0];
    }

    for (int T = 0; T < 32; ++T) {
        const _Float16* lb = lds + (T & 1) * 32768;
        // [invariant: af0,bf0 of tile T in flight (8 lgkm); stage T+1 <=8 vm]

        // ---- issue g1 reads (A m4-7 kk0: 4) ----
#pragma unroll
        for (int m = 0; m < 4; ++m) af1[m] = *(const half8*)&lb[aRow + ((m + 4) << 10) + c0];
        LGKM(4);   // retires g0's 8 (12 -> 4)
        SCHED0();
        __builtin_amdgcn_s_setprio(1);
#pragma unroll
        for (int m = 0; m < 4; ++m)
#pragma unroll
            for (int n = 0; n < 4; ++n)
                acc[m][n] = __builtin_amdgcn_mfma_f32_16x16x32_f16(af0[m], bf0[n], acc[m][n], 0, 0, 0);
        __builtin_amdgcn_s_setprio(0);
        SCHED0();

        // ---- issue g2 reads (A m0-3 kk1: 4, B n0-3 kk1: 4) ----
#pragma unroll
        for (int m = 0; m < 4; ++m) af2[m] = *(const half8*)&lb[aRow + (m << 10) + c1];
#pragma unroll
        for (int n = 0; n < 4; ++n) bf1[n] = *(const half8*)&lb[bRow + (n << 10) + c1];
        LGKM(8);   // retires g1's 4 (12 -> 8)
        SCHED0();
        __builtin_amdgcn_s_setprio(1);
#pragma unroll
        for (int m = 0; m < 4; ++m)
#pragma unroll
            for (int n = 0; n < 4; ++n)
                acc[m + 4][n] = __builtin_amdgcn_mfma_f32_16x16x32_f16(af1[m], bf0[n], acc[m + 4][n], 0, 0, 0);
        __builtin_amdgcn_s_setprio(0);
        SCHED0();

        // ---- issue g3 reads (A m4-7 kk1: 4) ----
#pragma unroll
        for (int m = 0; m < 4; ++m) af3[m] = *(const half8*)&lb[aRow + ((m + 4) << 10) + c1];
        LGKM(4);   // retires g2's 8 (12 -> 4)
        SCHED0();
        __builtin_amdgcn_s_setprio(1);
#pragma unroll
        for (int m = 0; m < 4; ++m)
#pragma unroll
            for (int n = 0; n < 4; ++n)
                acc[m][n] = __builtin_amdgcn_mfma_f32_16x16x32_f16(af2[m], bf1[n], acc[m][n], 0, 0, 0);
        __builtin_amdgcn_s_setprio(0);
        SCHED0();

        LGKM(0);   // g3 retired: this wave done reading tile T
        __builtin_amdgcn_s_barrier();          // barrier #1: ALL waves done with tile T
        if (T < 30) { stA(T + 2, 0); stA(T + 2, 1); stB(T + 2, 0); stB(T + 2, 1); }
        if (T < 30) { VMCNT(8); }              // stage T+1 retired (wave-local)
        else        { VMCNT(0); }
        __builtin_amdgcn_s_barrier();          // barrier #2: tile T+1 resident block-wide
        asm volatile("" ::: "memory");

        // ---- issue g0 reads of tile T+1 (8); then MFMA g3 overlaps them ----
        if (T < 31) {
            const _Float16* ln = lds + ((T + 1) & 1) * 32768;
#pragma unroll
            for (int m = 0; m < 4; ++m) af0[m] = *(const half8*)&ln[aRow + (m << 10) + c0];
#pragma unroll
            for (int n = 0; n < 4; ++n) bf0[n] = *(const half8*)&ln[bRow + (n << 10) + c0];
        }
        SCHED0();
        __builtin_amdgcn_s_setprio(1);
#pragma unroll
        for (int m = 0; m < 4; ++m)
#pragma unroll
            for (int n = 0; n < 4; ++n)
                acc[m + 4][n] = __builtin_amdgcn_mfma_f32_16x16x32_f16(af3[m], bf1[n], acc[m + 4][n], 0, 0, 0);
        __builtin_amdgcn_s_setprio(0);
        SCHED0();
    }

    // epilogue: C/D layout col=lane&15, row=(lane>>4)*4+j  [m89-verified]
    const int cr = lq << 2;
    const int cc = lane & 15;
#pragma unroll
    for (int m = 0; m < 8; ++m) {
#pragma unroll
        for (int n = 0; n < 4; ++n) {
            const size_t o0 = (size_t)(brow + wr + m * 16 + cr) * NN
                            + (bcol + wc + n * 16 + cc);
#pragma unroll
            for (int j = 0; j < 4; ++j)
                C[o0 + (size_t)j * NN] = acc[m][n][j];
        }
    }
}

// ================= generic GEMM (input/output projections) =================
// EPI 1: v += bias; oSta = f16(v); oS = f16(tanh(v))
// EPI 2: C[o] = v + bias
template<int EPI>
__global__ __launch_bounds__(256)
void gemm_bt(const _Float16* __restrict__ A, const _Float16* __restrict__ B,
             float* __restrict__ C, const float* __restrict__ bias,
             _Float16* __restrict__ oSta, _Float16* __restrict__ oS,
             int M, int N, int K)
{
    __shared__ _Float16 As[128 * 32];
    __shared__ _Float16 Bs[128 * 32];
    const int tid  = threadIdx.x;
    const int wid  = tid >> 6;
    const int lane = tid & 63;
    const int wr = (wid >> 1) * 64;
    const int wc = (wid & 1) * 64;
    const int brow = blockIdx.y * 128;
    const int bcol = blockIdx.x * 128;

    f32x4 acc[4][4];
#pragma unroll
    for (int m = 0; m < 4; ++m)
#pragma unroll
        for (int n = 0; n < 4; ++n) acc[m][n] = (f32x4){0.f, 0.f, 0.f, 0.f};

    const int ldr = tid >> 2;
    const int ldc = (tid & 3) * 8;
    const int wbase = (wid << 4) * 32;
    const int kq = (lane >> 4) * 8;
    const int lr = lane & 15;

    for (int k0 = 0; k0 < K; k0 += 32) {
        __syncthreads();
        gload_lds16(A + (size_t)(brow + ldr) * K + k0 + ldc, As + wbase);
        gload_lds16(A + (size_t)(brow + 64 + ldr) * K + k0 + ldc, As + 64 * 32 + wbase);
        gload_lds16(B + (size_t)(bcol + ldr) * K + k0 + ldc, Bs + wbase);
        gload_lds16(B + (size_t)(bcol + 64 + ldr) * K + k0 + ldc, Bs + 64 * 32 + wbase);
        __syncthreads();

        half8 af[4], bf[4];
#pragma unroll
        for (int m = 0; m < 4; ++m)
            af[m] = *(const half8*)&As[(wr + m * 16 + lr) * 32 + kq];
#pragma unroll
        for (int n = 0; n < 4; ++n)
            bf[n] = *(const half8*)&Bs[(wc + n * 16 + lr) * 32 + kq];
#pragma unroll
        for (int m = 0; m < 4; ++m)
#pragma unroll
            for (int n = 0; n < 4; ++n)
                acc[m][n] = __builtin_amdgcn_mfma_f32_16x16x32_f16(af[m], bf[n], acc[m][n], 0, 0, 0);
    }

    const int cr = (lane >> 4) * 4;
    const int cc = lane & 15;
#pragma unroll
    for (int m = 0; m < 4; ++m) {
#pragma unroll
        for (int n = 0; n < 4; ++n) {
            const int ccol = bcol + wc + n * 16 + cc;
#pragma unroll
            for (int j = 0; j < 4; ++j) {
                const int crow = brow + wr + m * 16 + cr + j;
                float v = acc[m][n][j];
                const size_t o = (size_t)crow * N + ccol;
                if (EPI == 1) {
                    v += bias[ccol];
                    oSta[o] = (_Float16)v;
                    oS[o] = (_Float16)tanhf(v);
                } else {
                    C[o] = v + bias[ccol];
                }
            }
        }
    }
}

// ================= small prep / elementwise kernels =================
__global__ void cvt_f16(const float* __restrict__ in, _Float16* __restrict__ out, int n4) {
    int i = blockIdx.x * blockDim.x + threadIdx.x;
    if (i < n4) {
        f32x4 v = *(const f32x4*)&in[(size_t)i * 4];
        half4 h;
        h[0] = (_Float16)v[0]; h[1] = (_Float16)v[1];
        h[2] = (_Float16)v[2]; h[3] = (_Float16)v[3];
        *(half4*)&out[(size_t)i * 4] = h;
    }
}

__global__ void transmul2(const float* __restrict__ W, const float* __restrict__ J,
                          const float* __restrict__ Mk,
                          _Float16* __restrict__ effT, _Float16* __restrict__ JmT) {
    __shared__ float tw[32][33];
    __shared__ float tj[32][33];
    const int bx = blockIdx.x * 32, by = blockIdx.y * 32;
    const int tx = threadIdx.x, ty0 = threadIdx.y;
#pragma unroll
    for (int r = 0; r < 4; ++r) {
        int ty = ty0 + r * 8;
        size_t idx = (size_t)(by + ty) * NN + bx + tx;
        float mv = Mk[idx];
        tw[ty][tx] = W[idx] * mv;
        tj[ty][tx] = J[idx] * mv;
    }
    __syncthreads();
#pragma unroll
    for (int r = 0; r < 4; ++r) {
        int ty = ty0 + r * 8;
        size_t o = (size_t)(bx + ty) * NN + by + tx;
        effT[o] = (_Float16)tw[tx][ty];
        JmT[o]  = (_Float16)tj[tx][ty];
    }
}

__global__ void tsc_kernel(const float* __restrict__ theta, float* __restrict__ Tsc) {
    int i = blockIdx.x * blockDim.x + threadIdx.x;
    if (i < NN) Tsc[i] = fabsf(sinf(2.0f * theta[i])) * 0.1f;
}

__global__ void step_kernel(const float* __restrict__ signal, const float* __restrict__ sJ,
                            const float* __restrict__ noise, const float* __restrict__ Tsc,
                            const float* __restrict__ lamp,
                            _Float16* __restrict__ stateH, _Float16* __restrict__ sH) {
    const int i4 = blockIdx.x * blockDim.x + threadIdx.x;
    const float lam = lamp[0];
    const size_t base = (size_t)i4 * 4;
    f32x4 sg = *(const f32x4*)&signal[base];
    f32x4 dj = *(const f32x4*)&sJ[base];
    f32x4 nz = *(const f32x4*)&noise[base];
    const int col4 = (int)(base & (NN - 1));
    f32x4 tv = *(const f32x4*)&Tsc[col4];
    half4 so = *(const half4*)&sH[base];
    half4 hs, hn;
#pragma unroll
    for (int j = 0; j < 4; ++j) {
        float s = (float)so[j];
        float arg = sg[j] + lam * (dj[j] * s) + nz[j] * tv[j];
        float st = tanhf(arg);
        hs[j] = (_Float16)st;
        hn[j] = (_Float16)tanhf(st);
    }
    *(half4*)&stateH[base] = hs;
    *(half4*)&sH[base] = hn;
}

extern "C" void kernel_launch(void* const* d_in, const int* in_sizes, int n_in,
                              void* d_out, int out_size, void* d_ws, size_t ws_size,
                              hipStream_t stream) {
    const float* x       = (const float*)d_in[0];
    const float* W_in    = (const float*)d_in[1];
    const float* b_in    = (const float*)d_in[2];
    const float* weights = (const float*)d_in[3];
    const float* Jmat    = (const float*)d_in[4];
    const float* theta   = (const float*)d_in[5];
    const float* lam     = (const float*)d_in[6];
    const float* mask    = (const float*)d_in[7];
    const float* noise   = (const float*)d_in[8];
    const float* W_out   = (const float*)d_in[9];
    const float* b_out   = (const float*)d_in[10];
    float* out = (float*)d_out;

    char* w = (char*)d_ws;
    auto alloc = [&](size_t b) { char* p = w; w += (b + 255) & ~(size_t)255; return p; };
    _Float16* xh     = (_Float16*)alloc((size_t)TOKENS * IN_DIM * 2);
    _Float16* WinH   = (_Float16*)alloc((size_t)NN * IN_DIM * 2);
    _Float16* WoutH  = (_Float16*)alloc((size_t)OUT_DIM * NN * 2);
    _Float16* effT   = (_Float16*)alloc((size_t)NN * NN * 2);
    _Float16* JmT    = (_Float16*)alloc((size_t)NN * NN * 2);
    _Float16* stateH = (_Float16*)alloc((size_t)TOKENS * NN * 2);
    _Float16* sH     = (_Float16*)alloc((size_t)TOKENS * NN * 2);
    float* Tsc       = (float*)alloc((size_t)NN * 4);
    float* signal    = (float*)alloc((size_t)TOKENS * NN * 4);
    float* sJ        = (float*)alloc((size_t)TOKENS * NN * 4);

    cvt_f16<<<TOKENS * IN_DIM / 4 / 256, 256, 0, stream>>>(x, xh, TOKENS * IN_DIM / 4);
    cvt_f16<<<NN * IN_DIM / 4 / 256, 256, 0, stream>>>(W_in, WinH, NN * IN_DIM / 4);
    cvt_f16<<<OUT_DIM * NN / 4 / 256, 256, 0, stream>>>(W_out, WoutH, OUT_DIM * NN / 4);
    transmul2<<<dim3(NN / 32, NN / 32), dim3(32, 8), 0, stream>>>(weights, Jmat, mask, effT, JmT);
    tsc_kernel<<<NN / 256, 256, 0, stream>>>(theta, Tsc);

    // state = x @ W_in.T + b_in
    gemm_bt<1><<<dim3(NN / 128, TOKENS / 128), 256, 0, stream>>>(
        xh, WinH, nullptr, b_in, stateH, sH, TOKENS, NN, IN_DIM);

    for (int t = 0; t < TSTEPS; ++t) {
        dual_gemm<<<256, 512, 0, stream>>>(stateH, effT, signal, sH, JmT, sJ);
        step_kernel<<<TOKENS * NN / 4 / 256, 256, 0, stream>>>(
            signal, sJ, noise + (size_t)t * TOKENS * NN, Tsc, lam, stateH, sH);
    }

    // out = state @ W_out.T + b_out
    gemm_bt<2><<<dim3(OUT_DIM / 128, TOKENS / 128), 256, 0, stream>>>(
        stateH, WoutH, out, b_out, nullptr, nullptr, TOKENS, OUT_DIM, NN);
}

// Round 9
// 341.100 us; speedup vs baseline: 1.9590x; 1.0859x over previous
//
#include <hip/hip_runtime.h>
#include <hip/hip_fp16.h>

#define TOKENS 4096
#define NN 2048
#define IN_DIM 1024
#define OUT_DIM 1024
#define TSTEPS 3

typedef _Float16 half8 __attribute__((ext_vector_type(8)));
typedef _Float16 half4 __attribute__((ext_vector_type(4)));
typedef float f32x4 __attribute__((ext_vector_type(4)));

__device__ __forceinline__ void gload_lds16(const void* g, void* l) {
    __builtin_amdgcn_global_load_lds(
        (const __attribute__((address_space(1))) unsigned*)g,
        (__attribute__((address_space(3))) unsigned*)l, 16, 0, 0);
}

#define LGKM(N) asm volatile("s_waitcnt lgkmcnt(" #N ")" ::: "memory")
#define VMCNT(N) asm volatile("s_waitcnt vmcnt(" #N ")" ::: "memory")
#define SCHED0() __builtin_amdgcn_sched_barrier(0)

// ================= pipelined dual GEMM (recurrent step) =================
// As round 8 (69 us, 991 TF, race-clean) but epilogue writes f16.
__global__ __launch_bounds__(512, 2)
void dual_gemm(const _Float16* __restrict__ A0g, const _Float16* __restrict__ B0g,
               _Float16* __restrict__ C0,
               const _Float16* __restrict__ A1g, const _Float16* __restrict__ B1g,
               _Float16* __restrict__ C1)
{
    __shared__ __align__(16) _Float16 lds[2 * 32768];   // 128 KiB
    const int tid  = threadIdx.x;
    const int wid  = tid >> 6;
    const int lane = tid & 63;

    const int raw  = blockIdx.x;
    const int widx = (raw & 7) * 32 + (raw >> 3);
    const int g    = widx >> 7;
    const int bid  = widx & 127;
    const int by = bid >> 3;
    const int bx = bid & 7;
    const _Float16* __restrict__ A = g ? A1g : A0g;
    const _Float16* __restrict__ B = g ? B1g : B0g;
    _Float16* __restrict__ C = g ? C1 : C0;
    const int brow = by << 8;
    const int bcol = bx << 8;

    const int sr = tid >> 3;
    const int sc = ((tid & 7) ^ (sr & 7)) << 3;
    const _Float16* gA = A + (size_t)(brow + sr) * NN + sc;
    const _Float16* gB = B + (size_t)(bcol + sr) * NN + sc;
    const int ldst = wid << 9;

    auto stA = [&](int T, int h) {
        _Float16* l = lds + (T & 1) * 32768 + h * 8192;
        const _Float16* p = gA + (size_t)(h << 7) * NN + (T << 6);
        gload_lds16(p,           l + ldst);
        gload_lds16(p + 64 * NN, l + 4096 + ldst);
    };
    auto stB = [&](int T, int h) {
        _Float16* l = lds + (T & 1) * 32768 + 16384 + h * 8192;
        const _Float16* p = gB + (size_t)(h << 7) * NN + (T << 6);
        gload_lds16(p,           l + ldst);
        gload_lds16(p + 64 * NN, l + 4096 + ldst);
    };

    const int wr = (wid >> 2) << 7;
    const int wc = (wid & 3) << 6;
    const int lr = lane & 15;
    const int lq = lane >> 4;
    const int x7 = lr & 7;
    const int c0 = (lq ^ x7) << 3;
    const int c1 = ((4 + lq) ^ x7) << 3;
    const int aRow = (wr + lr) << 6;
    const int bRow = 16384 + ((wc + lr) << 6);

    f32x4 acc[8][4];
#pragma unroll
    for (int m = 0; m < 8; ++m)
#pragma unroll
        for (int n = 0; n < 4; ++n) acc[m][n] = (f32x4){0.f, 0.f, 0.f, 0.f};

    half8 af0[4], af1[4], af2[4], af3[4], bf0[4], bf1[4];

    stA(0, 0); stA(0, 1); stB(0, 0); stB(0, 1);
    stA(1, 0); stA(1, 1); stB(1, 0); stB(1, 1);
    VMCNT(8);
    __builtin_amdgcn_s_barrier();
    {
        const _Float16* lb = lds;
#pragma unroll
        for (int m = 0; m < 4; ++m) af0[m] = *(const half8*)&lb[aRow + (m << 10) + c0];
#pragma unroll
        for (int n = 0; n < 4; ++n) bf0[n] = *(const half8*)&lb[bRow + (n << 10) + c0];
    }

    for (int T = 0; T < 32; ++T) {
        const _Float16* lb = lds + (T & 1) * 32768;

#pragma unroll
        for (int m = 0; m < 4; ++m) af1[m] = *(const half8*)&lb[aRow + ((m + 4) << 10) + c0];
        LGKM(4);
        SCHED0();
        __builtin_amdgcn_s_setprio(1);
#pragma unroll
        for (int m = 0; m < 4; ++m)
#pragma unroll
            for (int n = 0; n < 4; ++n)
                acc[m][n] = __builtin_amdgcn_mfma_f32_16x16x32_f16(af0[m], bf0[n], acc[m][n], 0, 0, 0);
        __builtin_amdgcn_s_setprio(0);
        SCHED0();

#pragma unroll
        for (int m = 0; m < 4; ++m) af2[m] = *(const half8*)&lb[aRow + (m << 10) + c1];
#pragma unroll
        for (int n = 0; n < 4; ++n) bf1[n] = *(const half8*)&lb[bRow + (n << 10) + c1];
        LGKM(8);
        SCHED0();
        __builtin_amdgcn_s_setprio(1);
#pragma unroll
        for (int m = 0; m < 4; ++m)
#pragma unroll
            for (int n = 0; n < 4; ++n)
                acc[m + 4][n] = __builtin_amdgcn_mfma_f32_16x16x32_f16(af1[m], bf0[n], acc[m + 4][n], 0, 0, 0);
        __builtin_amdgcn_s_setprio(0);
        SCHED0();

#pragma unroll
        for (int m = 0; m < 4; ++m) af3[m] = *(const half8*)&lb[aRow + ((m + 4) << 10) + c1];
        LGKM(4);
        SCHED0();
        __builtin_amdgcn_s_setprio(1);
#pragma unroll
        for (int m = 0; m < 4; ++m)
#pragma unroll
            for (int n = 0; n < 4; ++n)
                acc[m][n] = __builtin_amdgcn_mfma_f32_16x16x32_f16(af2[m], bf1[n], acc[m][n], 0, 0, 0);
        __builtin_amdgcn_s_setprio(0);
        SCHED0();

        LGKM(0);
        __builtin_amdgcn_s_barrier();
        if (T < 30) { stA(T + 2, 0); stA(T + 2, 1); stB(T + 2, 0); stB(T + 2, 1); }
        if (T < 30) { VMCNT(8); }
        else        { VMCNT(0); }
        __builtin_amdgcn_s_barrier();
        asm volatile("" ::: "memory");

        if (T < 31) {
            const _Float16* ln = lds + ((T + 1) & 1) * 32768;
#pragma unroll
            for (int m = 0; m < 4; ++m) af0[m] = *(const half8*)&ln[aRow + (m << 10) + c0];
#pragma unroll
            for (int n = 0; n < 4; ++n) bf0[n] = *(const half8*)&ln[bRow + (n << 10) + c0];
        }
        SCHED0();
        __builtin_amdgcn_s_setprio(1);
#pragma unroll
        for (int m = 0; m < 4; ++m)
#pragma unroll
            for (int n = 0; n < 4; ++n)
                acc[m + 4][n] = __builtin_amdgcn_mfma_f32_16x16x32_f16(af3[m], bf1[n], acc[m + 4][n], 0, 0, 0);
        __builtin_amdgcn_s_setprio(0);
        SCHED0();
    }

    const int cr = lq << 2;
    const int cc = lane & 15;
#pragma unroll
    for (int m = 0; m < 8; ++m) {
#pragma unroll
        for (int n = 0; n < 4; ++n) {
            const size_t o0 = (size_t)(brow + wr + m * 16 + cr) * NN
                            + (bcol + wc + n * 16 + cc);
#pragma unroll
            for (int j = 0; j < 4; ++j)
                C[o0 + (size_t)j * NN] = (_Float16)acc[m][n][j];
        }
    }
}

// ============ pipelined 128x128 GEMM (input/output projections) ============
// 4 waves (2Mx2N, 64x64/wave), BK=64, 2 bufs x 32 KiB = 64 KiB -> 2 blocks/CU.
// Same counted-wait ledger discipline as dual_gemm (8 calls/tile, vmcnt(8)).
// EPI 1: v+=bias; oSta=f16(v); oS=f16(tanh(v)).  EPI 2: Cout=v+bias (f32).
template<int EPI>
__global__ __launch_bounds__(256, 2)
void pgemm(const _Float16* __restrict__ A, const _Float16* __restrict__ B,
           float* __restrict__ Cout, const float* __restrict__ bias,
           _Float16* __restrict__ oSta, _Float16* __restrict__ oS,
           int K, int N, int nbxLog2)
{
    __shared__ __align__(16) _Float16 lds[2 * 16384];   // 64 KiB
    const int tid  = threadIdx.x;
    const int wid  = tid >> 6;
    const int lane = tid & 63;

    const int raw  = blockIdx.x;
    const int cpx  = gridDim.x >> 3;
    const int widx = (raw & 7) * cpx + (raw >> 3);
    const int by = widx >> nbxLog2;
    const int bx = widx & ((1 << nbxLog2) - 1);
    const int brow = by << 7;
    const int bcol = bx << 7;

    // staging: call = 256 thr x 16 B = 4 KB = 32 rows x 64 f16; 4 calls per tile half
    const int sr = tid >> 3;                      // 0..31
    const int sc = ((tid & 7) ^ (sr & 7)) << 3;
    const _Float16* gA = A + (size_t)(brow + sr) * K + sc;
    const _Float16* gB = B + (size_t)(bcol + sr) * K + sc;
    const int ldst = wid << 9;

    auto stA = [&](int T) {   // 4 calls: A[128][64] -> lds[0..8192)
        _Float16* l = lds + (T & 1) * 16384;
        const _Float16* p = gA + (T << 6);
#pragma unroll
        for (int r = 0; r < 4; ++r)
            gload_lds16(p + (size_t)(r * 32) * K, l + r * 2048 + ldst);
    };
    auto stB = [&](int T) {   // 4 calls: B[128][64] -> lds[8192..16384)
        _Float16* l = lds + (T & 1) * 16384 + 8192;
        const _Float16* p = gB + (T << 6);
#pragma unroll
        for (int r = 0; r < 4; ++r)
            gload_lds16(p + (size_t)(r * 32) * K, l + r * 2048 + ldst);
    };

    const int wr = (wid >> 1) << 6;   // 0 / 64
    const int wc = (wid & 1) << 6;    // 0 / 64
    const int lr = lane & 15;
    const int lq = lane >> 4;
    const int x7 = lr & 7;
    const int c0 = (lq ^ x7) << 3;
    const int c1 = ((4 + lq) ^ x7) << 3;
    const int aRow = (wr + lr) << 6;
    const int bRow = 8192 + ((wc + lr) << 6);

    f32x4 acc[4][4];
#pragma unroll
    for (int m = 0; m < 4; ++m)
#pragma unroll
        for (int n = 0; n < 4; ++n) acc[m][n] = (f32x4){0.f, 0.f, 0.f, 0.f};

    half8 af0[4], af1[4], bf0[4], bf1[4];
    const int NT = K >> 6;

    stA(0); stB(0); stA(1); stB(1);
    VMCNT(8);
    __builtin_amdgcn_s_barrier();
    {   // g0 of tile 0: A kk0 + B kk0
        const _Float16* lb = lds;
#pragma unroll
        for (int m = 0; m < 4; ++m) af0[m] = *(const half8*)&lb[aRow + (m << 10) + c0];
#pragma unroll
        for (int n = 0; n < 4; ++n) bf0[n] = *(const half8*)&lb[bRow + (n << 10) + c0];
    }

    for (int T = 0; T < NT; ++T) {
        const _Float16* lb = lds + (T & 1) * 16384;

        // issue g1 (A kk1 + B kk1); wait g0; MFMA kk0
#pragma unroll
        for (int m = 0; m < 4; ++m) af1[m] = *(const half8*)&lb[aRow + (m << 10) + c1];
#pragma unroll
        for (int n = 0; n < 4; ++n) bf1[n] = *(const half8*)&lb[bRow + (n << 10) + c1];
        LGKM(8);
        SCHED0();
        __builtin_amdgcn_s_setprio(1);
#pragma unroll
        for (int m = 0; m < 4; ++m)
#pragma unroll
            for (int n = 0; n < 4; ++n)
                acc[m][n] = __builtin_amdgcn_mfma_f32_16x16x32_f16(af0[m], bf0[n], acc[m][n], 0, 0, 0);
        __builtin_amdgcn_s_setprio(0);
        SCHED0();

        LGKM(0);                               // g1 retired; tile T reads done
        __builtin_amdgcn_s_barrier();          // barrier #1
        if (T < NT - 2) { stA(T + 2); stB(T + 2); VMCNT(8); }
        else if (T == NT - 2) { VMCNT(0); }
        __builtin_amdgcn_s_barrier();          // barrier #2: tile T+1 resident
        asm volatile("" ::: "memory");

        if (T < NT - 1) {
            const _Float16* ln = lds + ((T + 1) & 1) * 16384;
#pragma unroll
            for (int m = 0; m < 4; ++m) af0[m] = *(const half8*)&ln[aRow + (m << 10) + c0];
#pragma unroll
            for (int n = 0; n < 4; ++n) bf0[n] = *(const half8*)&ln[bRow + (n << 10) + c0];
        }
        SCHED0();
        __builtin_amdgcn_s_setprio(1);
#pragma unroll
        for (int m = 0; m < 4; ++m)
#pragma unroll
            for (int n = 0; n < 4; ++n)
                acc[m][n] = __builtin_amdgcn_mfma_f32_16x16x32_f16(af1[m], bf1[n], acc[m][n], 0, 0, 0);
        __builtin_amdgcn_s_setprio(0);
        SCHED0();
    }

    const int cr = lq << 2;
    const int cc = lane & 15;
#pragma unroll
    for (int m = 0; m < 4; ++m) {
#pragma unroll
        for (int n = 0; n < 4; ++n) {
            const int ccol = bcol + wc + n * 16 + cc;
#pragma unroll
            for (int j = 0; j < 4; ++j) {
                const int crow = brow + wr + m * 16 + cr + j;
                float v = acc[m][n][j] + bias[ccol];
                const size_t o = (size_t)crow * N + ccol;
                if (EPI == 1) {
                    oSta[o] = (_Float16)v;
                    oS[o] = (_Float16)tanhf(v);
                } else {
                    Cout[o] = v;
                }
            }
        }
    }
}

// ================= small prep / elementwise kernels =================
__global__ void cvt_f16(const float* __restrict__ in, _Float16* __restrict__ out, int n4) {
    int i = blockIdx.x * blockDim.x + threadIdx.x;
    if (i < n4) {
        f32x4 v = *(const f32x4*)&in[(size_t)i * 4];
        half4 h;
        h[0] = (_Float16)v[0]; h[1] = (_Float16)v[1];
        h[2] = (_Float16)v[2]; h[3] = (_Float16)v[3];
        *(half4*)&out[(size_t)i * 4] = h;
    }
}

__global__ void transmul2(const float* __restrict__ W, const float* __restrict__ J,
                          const float* __restrict__ Mk,
                          _Float16* __restrict__ effT, _Float16* __restrict__ JmT) {
    __shared__ float tw[32][33];
    __shared__ float tj[32][33];
    const int bx = blockIdx.x * 32, by = blockIdx.y * 32;
    const int tx = threadIdx.x, ty0 = threadIdx.y;
#pragma unroll
    for (int r = 0; r < 4; ++r) {
        int ty = ty0 + r * 8;
        size_t idx = (size_t)(by + ty) * NN + bx + tx;
        float mv = Mk[idx];
        tw[ty][tx] = W[idx] * mv;
        tj[ty][tx] = J[idx] * mv;
    }
    __syncthreads();
#pragma unroll
    for (int r = 0; r < 4; ++r) {
        int ty = ty0 + r * 8;
        size_t o = (size_t)(bx + ty) * NN + by + tx;
        effT[o] = (_Float16)tw[tx][ty];
        JmT[o]  = (_Float16)tj[tx][ty];
    }
}

__global__ void tsc_kernel(const float* __restrict__ theta, float* __restrict__ Tsc) {
    int i = blockIdx.x * blockDim.x + threadIdx.x;
    if (i < NN) Tsc[i] = fabsf(sinf(2.0f * theta[i])) * 0.1f;
}

__global__ void step_kernel(const _Float16* __restrict__ signalH, const _Float16* __restrict__ sJH,
                            const float* __restrict__ noise, const float* __restrict__ Tsc,
                            const float* __restrict__ lamp,
                            _Float16* __restrict__ stateH, _Float16* __restrict__ sH) {
    const int i4 = blockIdx.x * blockDim.x + threadIdx.x;
    const float lam = lamp[0];
    const size_t base = (size_t)i4 * 4;
    half4 sg = *(const half4*)&signalH[base];
    half4 dj = *(const half4*)&sJH[base];
    f32x4 nz = *(const f32x4*)&noise[base];
    const int col4 = (int)(base & (NN - 1));
    f32x4 tv = *(const f32x4*)&Tsc[col4];
    half4 so = *(const half4*)&sH[base];
    half4 hs, hn;
#pragma unroll
    for (int j = 0; j < 4; ++j) {
        float s = (float)so[j];
        float arg = (float)sg[j] + lam * ((float)dj[j] * s) + nz[j] * tv[j];
        float st = tanhf(arg);
        hs[j] = (_Float16)st;
        hn[j] = (_Float16)tanhf(st);
    }
    *(half4*)&stateH[base] = hs;
    *(half4*)&sH[base] = hn;
}

extern "C" void kernel_launch(void* const* d_in, const int* in_sizes, int n_in,
                              void* d_out, int out_size, void* d_ws, size_t ws_size,
                              hipStream_t stream) {
    const float* x       = (const float*)d_in[0];
    const float* W_in    = (const float*)d_in[1];
    const float* b_in    = (const float*)d_in[2];
    const float* weights = (const float*)d_in[3];
    const float* Jmat    = (const float*)d_in[4];
    const float* theta   = (const float*)d_in[5];
    const float* lam     = (const float*)d_in[6];
    const float* mask    = (const float*)d_in[7];
    const float* noise   = (const float*)d_in[8];
    const float* W_out   = (const float*)d_in[9];
    const float* b_out   = (const float*)d_in[10];
    float* out = (float*)d_out;

    char* w = (char*)d_ws;
    auto alloc = [&](size_t b) { char* p = w; w += (b + 255) & ~(size_t)255; return p; };
    _Float16* xh      = (_Float16*)alloc((size_t)TOKENS * IN_DIM * 2);
    _Float16* WinH    = (_Float16*)alloc((size_t)NN * IN_DIM * 2);
    _Float16* WoutH   = (_Float16*)alloc((size_t)OUT_DIM * NN * 2);
    _Float16* effT    = (_Float16*)alloc((size_t)NN * NN * 2);
    _Float16* JmT     = (_Float16*)alloc((size_t)NN * NN * 2);
    _Float16* stateH  = (_Float16*)alloc((size_t)TOKENS * NN * 2);
    _Float16* sH      = (_Float16*)alloc((size_t)TOKENS * NN * 2);
    _Float16* signalH = (_Float16*)alloc((size_t)TOKENS * NN * 2);
    _Float16* sJH     = (_Float16*)alloc((size_t)TOKENS * NN * 2);
    float* Tsc        = (float*)alloc((size_t)NN * 4);

    cvt_f16<<<TOKENS * IN_DIM / 4 / 256, 256, 0, stream>>>(x, xh, TOKENS * IN_DIM / 4);
    cvt_f16<<<NN * IN_DIM / 4 / 256, 256, 0, stream>>>(W_in, WinH, NN * IN_DIM / 4);
    cvt_f16<<<OUT_DIM * NN / 4 / 256, 256, 0, stream>>>(W_out, WoutH, OUT_DIM * NN / 4);
    transmul2<<<dim3(NN / 32, NN / 32), dim3(32, 8), 0, stream>>>(weights, Jmat, mask, effT, JmT);
    tsc_kernel<<<NN / 256, 256, 0, stream>>>(theta, Tsc);

    // state = x @ W_in.T + b_in   (M=4096, N=2048, K=1024; nbx=16)
    pgemm<1><<<(TOKENS / 128) * (NN / 128), 256, 0, stream>>>(
        xh, WinH, nullptr, b_in, stateH, sH, IN_DIM, NN, 4);

    for (int t = 0; t < TSTEPS; ++t) {
        dual_gemm<<<256, 512, 0, stream>>>(stateH, effT, signalH, sH, JmT, sJH);
        step_kernel<<<TOKENS * NN / 4 / 256, 256, 0, stream>>>(
            signalH, sJH, noise + (size_t)t * TOKENS * NN, Tsc, lam, stateH, sH);
    }

    // out = state @ W_out.T + b_out   (M=4096, N=1024, K=2048; nbx=8)
    pgemm<2><<<(TOKENS / 128) * (OUT_DIM / 128), 256, 0, stream>>>(
        stateH, WoutH, out, b_out, nullptr, nullptr, NN, OUT_DIM, 3);
}